// Round 1
// baseline (1169.617 us; speedup 1.0000x reference)
//
#include <hip/hip_runtime.h>
#include <hip/hip_bf16.h>
#include <stdint.h>

// Problem: B=1, S_IMG=1536, S_TXT=512, D=3072, H=24, HD=128, R=32.
// Harness dtypes: ALL inputs float32, output float32. Internal MFMA in bf16.
typedef __hip_bfloat16 bf16;
typedef __attribute__((ext_vector_type(8))) short short8;   // 8 bf16 (16B)
typedef __attribute__((ext_vector_type(4))) short short4b;  // 4 bf16 (8B)
typedef __attribute__((ext_vector_type(4))) float floatx4;  // MFMA C/D

__device__ __forceinline__ short bfs(float x) {
    // RNE f32 -> bf16, returned as raw bits
    uint32_t u = __builtin_bit_cast(uint32_t, x);
    u += 0x7FFFu + ((u >> 16) & 1u);
    return (short)(u >> 16);
}
__device__ __forceinline__ float b2f(bf16 x) { return __bfloat162float(x); }

// async global->LDS, 16B per lane. LDS dest is wave-uniform base + lane*16,
// so per-lane dest pointers must be exactly base + lane*16 (linear layout).
__device__ __forceinline__ void load_lds16(const bf16* g, bf16* l) {
    __builtin_amdgcn_global_load_lds(
        (const __attribute__((address_space(1))) uint32_t*)g,
        (__attribute__((address_space(3))) uint32_t*)l, 16, 0, 0);
}

// ---------------------------------------------------------------------------
// f32 -> bf16 bulk convert. 8 elems/thread, grid = n/2048 blocks.
__global__ __launch_bounds__(256) void cvt_bf16(const float* __restrict__ X,
                                                bf16* __restrict__ Y) {
    const size_t i = ((size_t)blockIdx.x * 256 + threadIdx.x) * 8;
    const float4 v0 = *(const float4*)(X + i);
    const float4 v1 = *(const float4*)(X + i + 4);
    short8 o = { bfs(v0.x), bfs(v0.y), bfs(v0.z), bfs(v0.w),
                 bfs(v1.x), bfs(v1.y), bfs(v1.z), bfs(v1.w) };
    *(short8*)(Y + i) = o;
}

// ---------------------------------------------------------------------------
// upT[n][r] = up[r][n]   (up is [32][N] row-major f32 -> bf16)
__global__ __launch_bounds__(64) void transposeR(const float* __restrict__ U,
                                                 bf16* __restrict__ UT, int N) {
    const int n = blockIdx.x * 64 + threadIdx.x;
    #pragma unroll
    for (int r = 0; r < 32; ++r)
        UT[(size_t)n * 32 + r] = __float2bfloat16(U[(size_t)r * N + n]);
}

// ---------------------------------------------------------------------------
// t[m][r] = sum_k x[m][k] * down[k][r]   (K=3072, R=32). One block per row m.
// x is bf16, down is f32, t written bf16.
__global__ __launch_bounds__(256) void downproj(const bf16* __restrict__ X,
                                                const float* __restrict__ Dn,
                                                bf16* __restrict__ T, int K) {
    const int m = blockIdx.x;
    const int n = threadIdx.x & 31;
    const int kg = threadIdx.x >> 5;           // 8 K-groups
    const bf16* x = X + (size_t)m * K;
    const int kc = K >> 3;                     // 384
    float acc = 0.f;
    #pragma unroll 4
    for (int k = kg * kc; k < (kg + 1) * kc; ++k)
        acc += b2f(x[k]) * Dn[(size_t)k * 32 + n];
    __shared__ float red[8][32];
    red[kg][n] = acc;
    __syncthreads();
    if (threadIdx.x < 32) {
        float s = 0.f;
        #pragma unroll
        for (int g = 0; g < 8; ++g) s += red[g][n];
        T[(size_t)m * 32 + n] = __float2bfloat16(s);
    }
}

// ---------------------------------------------------------------------------
// C = A @ B^T + t @ upT^T (+bias). A:[M][K], B:[N][K], t:[M][32], upT:[N][32],
// ALL bf16 in global. Staged to LDS via global_load_lds (no VALU in staging).
// Low-rank term is one extra K-step. mode 0: write C row-major [M][N] f32.
// mode 1: scatter to Q[h][s][128], K[h][s][128], V[h][128][s] (bf16).
__global__ __launch_bounds__(256) void gemm128(
    const bf16* __restrict__ A, const bf16* __restrict__ B,
    const bf16* __restrict__ T, const bf16* __restrict__ UpT,
    const float* __restrict__ bias, float* __restrict__ C,
    bf16* __restrict__ Qb, bf16* __restrict__ Kb, bf16* __restrict__ Vb,
    int M, int N, int K, int s_base, int mode)
{
    __shared__ __align__(16) bf16 As[128 * 32];
    __shared__ __align__(16) bf16 Bs[128 * 32];
    const int tid = threadIdx.x;
    const int lane = tid & 63, w = tid >> 6;
    const int wm = (w >> 1) * 64, wn = (w & 1) * 64;
    const int lr = lane & 15, lq = lane >> 4;

    // XCD-aware bijective swizzle (all grids here have nwg % 8 == 0)
    int bid = blockIdx.y * gridDim.x + blockIdx.x;
    const int cpx = (gridDim.x * gridDim.y) >> 3;
    bid = (bid & 7) * cpx + (bid >> 3);
    const int by = bid / gridDim.x, bx = bid - by * gridDim.x;
    const int m0 = by * 128, n0 = bx * 128;

    floatx4 acc[4][4] = {};
    const int ksteps = K >> 5;
    for (int kt = 0; kt <= ksteps; ++kt) {
        const bf16 *a_src, *b_src;
        int lda, ldb;
        if (kt < ksteps) {
            a_src = A + (size_t)m0 * K + kt * 32; lda = K;
            b_src = B + (size_t)n0 * K + kt * 32; ldb = K;
        } else {                                  // low-rank K-step
            a_src = T   + (size_t)m0 * 32; lda = 32;
            b_src = UpT + (size_t)n0 * 32; ldb = 32;
        }
        __syncthreads();
        // stage: 128 rows x 32 bf16 = 512 chunks of 16B per matrix
        #pragma unroll
        for (int it = 0; it < 2; ++it) {
            const int c = tid + it * 256;
            const int row = c >> 2, sub = c & 3;
            load_lds16(a_src + (size_t)row * lda + sub * 8, As + c * 8);
        }
        #pragma unroll
        for (int it = 0; it < 2; ++it) {
            const int c = tid + it * 256;
            const int row = c >> 2, sub = c & 3;
            load_lds16(b_src + (size_t)row * ldb + sub * 8, Bs + c * 8);
        }
        __syncthreads();
        short8 af[4], bfr[4];
        #pragma unroll
        for (int i = 0; i < 4; ++i)
            af[i] = *(const short8*)(As + (wm + i * 16 + lr) * 32 + lq * 8);
        #pragma unroll
        for (int j = 0; j < 4; ++j)
            bfr[j] = *(const short8*)(Bs + (wn + j * 16 + lr) * 32 + lq * 8);
        #pragma unroll
        for (int i = 0; i < 4; ++i)
            #pragma unroll
            for (int j = 0; j < 4; ++j)
                acc[i][j] = __builtin_amdgcn_mfma_f32_16x16x32_bf16(
                    af[i], bfr[j], acc[i][j], 0, 0, 0);
    }

    if (mode == 0) {
        #pragma unroll
        for (int j = 0; j < 4; ++j) {
            const int col = n0 + wn + j * 16 + lr;
            const float bv = bias ? bias[col] : 0.0f;
            #pragma unroll
            for (int i = 0; i < 4; ++i) {
                const int rowb = m0 + wm + i * 16 + lq * 4;
                #pragma unroll
                for (int r = 0; r < 4; ++r)
                    C[(size_t)(rowb + r) * N + col] = acc[i][j][r] + bv;
            }
        }
    } else {
        #pragma unroll
        for (int j = 0; j < 4; ++j) {
            const int col = n0 + wn + j * 16 + lr;
            const int which = col / 3072;
            const int cc = col - which * 3072;
            const int hh = cc >> 7, dd = cc & 127;
            #pragma unroll
            for (int i = 0; i < 4; ++i) {
                const int rowb = m0 + wm + i * 16 + lq * 4;
                #pragma unroll
                for (int r = 0; r < 4; ++r) {
                    const int s = s_base + rowb + r;
                    const bf16 v = __float2bfloat16(acc[i][j][r]);
                    if (which == 0)
                        Qb[((size_t)hh * 2048 + s) * 128 + dd] = v;
                    else if (which == 1)
                        Kb[((size_t)hh * 2048 + s) * 128 + dd] = v;
                    else
                        Vb[((size_t)hh * 128 + dd) * 2048 + s] = v;  // V^T
                }
            }
        }
    }
}

// ---------------------------------------------------------------------------
// RMSNorm (per (s,h) row of 128) + RoPE, in-place on Q and K (bf16 buffers).
// cos/sin/norm-weights are f32 inputs. 1 wave/block.
__global__ __launch_bounds__(64) void rmsrope(
    bf16* __restrict__ Qb, bf16* __restrict__ Kb,
    const float* __restrict__ cosb, const float* __restrict__ sinb,
    const float* __restrict__ nqw, const float* __restrict__ nkw,
    const float* __restrict__ naqw, const float* __restrict__ nakw)
{
    const int s = blockIdx.x & 2047;
    const int h = blockIdx.x >> 11;
    const int i = threadIdx.x;                       // pair index 0..63
    const float c  = cosb[s * 64 + i];
    const float sn = sinb[s * 64 + i];
    const bool txt = (s < 512);
    const size_t base = ((size_t)h * 2048 + s) * 128;

    {
        __hip_bfloat162* row = (__hip_bfloat162*)(Qb + base);
        __hip_bfloat162 pv = row[i];
        float x0 = b2f(pv.x), x1 = b2f(pv.y);
        float ss = x0 * x0 + x1 * x1;
        #pragma unroll
        for (int m = 1; m < 64; m <<= 1) ss += __shfl_xor(ss, m);
        const float rms = rsqrtf(ss * (1.0f / 128.0f) + 1e-5f);
        const float* nw = txt ? naqw : nqw;
        const float y0 = x0 * rms * nw[2 * i];
        const float y1 = x1 * rms * nw[2 * i + 1];
        __hip_bfloat162 o;
        o.x = __float2bfloat16(y0 * c - y1 * sn);
        o.y = __float2bfloat16(y0 * sn + y1 * c);
        row[i] = o;
    }
    {
        __hip_bfloat162* row = (__hip_bfloat162*)(Kb + base);
        __hip_bfloat162 pv = row[i];
        float x0 = b2f(pv.x), x1 = b2f(pv.y);
        float ss = x0 * x0 + x1 * x1;
        #pragma unroll
        for (int m = 1; m < 64; m <<= 1) ss += __shfl_xor(ss, m);
        const float rms = rsqrtf(ss * (1.0f / 128.0f) + 1e-5f);
        const float* nw = txt ? nakw : nkw;
        const float y0 = x0 * rms * nw[2 * i];
        const float y1 = x1 * rms * nw[2 * i + 1];
        __hip_bfloat162 o;
        o.x = __float2bfloat16(y0 * c - y1 * sn);
        o.y = __float2bfloat16(y0 * sn + y1 * c);
        row[i] = o;
    }
}

// ---------------------------------------------------------------------------
// Flash attention: block = 64 q-rows of one head; KV tiles of 64; 4 waves,
// each wave owns 16 q-rows x full HD=128. Online softmax in registers.
// Output attnb is bf16 [s][3072]. K/V staged via global_load_lds.
__global__ __launch_bounds__(256) void attn64(
    const bf16* __restrict__ Qb, const bf16* __restrict__ Kb,
    const bf16* __restrict__ Vb, bf16* __restrict__ attnb)
{
    __shared__ __align__(16) bf16 Ks[64 * 128];     // [kv][d]
    __shared__ __align__(16) bf16 VsT[128 * 64];    // [d][kv]
    __shared__ __align__(16) bf16 Ps[4][16][72];    // per-wave P, 72 keeps 16B align
    const int tid = threadIdx.x, lane = tid & 63, w = tid >> 6;
    const int lr = lane & 15, lq = lane >> 4;
    const int h = blockIdx.y, q0 = blockIdx.x * 64;
    const float scale = 0.08838834764831845f;   // 1/sqrt(128)

    // Q fragments for this wave's 16 rows (kept in registers whole kernel)
    const bf16* qrow = Qb + ((size_t)h * 2048 + q0 + w * 16 + lr) * 128;
    short8 qf[4];
    #pragma unroll
    for (int ks = 0; ks < 4; ++ks)
        qf[ks] = *(const short8*)(qrow + ks * 32 + lq * 8);

    floatx4 oacc[8] = {};
    float mrow[4] = {-1e30f, -1e30f, -1e30f, -1e30f};
    float lrow[4] = {0.f, 0.f, 0.f, 0.f};

    for (int kt = 0; kt < 32; ++kt) {
        const int kv0 = kt * 64;
        __syncthreads();
        // Ks: 64 rows x 128 cols = 1024 chunks of 16B (global_load_lds)
        #pragma unroll
        for (int it = 0; it < 4; ++it) {
            const int c = tid + it * 256;
            const int row = c >> 4, cg = c & 15;
            load_lds16(Kb + ((size_t)h * 2048 + kv0 + row) * 128 + cg * 8,
                       Ks + c * 8);
        }
        // VsT: 128 rows x 64 cols = 1024 chunks of 16B
        #pragma unroll
        for (int it = 0; it < 4; ++it) {
            const int c = tid + it * 256;
            const int row = c >> 3, cg = c & 7;
            load_lds16(Vb + ((size_t)h * 128 + row) * 2048 + kv0 + cg * 8,
                       VsT + c * 8);
        }
        __syncthreads();

        // S = Q K^T for 16 q x 64 kv
        floatx4 sacc[4] = {};
        #pragma unroll
        for (int ks = 0; ks < 4; ++ks)
            #pragma unroll
            for (int jt = 0; jt < 4; ++jt) {
                short8 kf = *(const short8*)(Ks + (jt * 16 + lr) * 128 + ks * 32 + lq * 8);
                sacc[jt] = __builtin_amdgcn_mfma_f32_16x16x32_bf16(qf[ks], kf, sacc[jt], 0, 0, 0);
            }

        // online softmax (lane holds rows lq*4+r, col lr of each 16-block)
        float alpha_r[4];
        #pragma unroll
        for (int r = 0; r < 4; ++r) {
            float s0 = sacc[0][r] * scale, s1 = sacc[1][r] * scale;
            float s2 = sacc[2][r] * scale, s3 = sacc[3][r] * scale;
            float mx = fmaxf(fmaxf(s0, s1), fmaxf(s2, s3));
            #pragma unroll
            for (int msk = 1; msk < 16; msk <<= 1)
                mx = fmaxf(mx, __shfl_xor(mx, msk));
            const float mn = fmaxf(mrow[r], mx);
            const float al = __expf(mrow[r] - mn);
            s0 = __expf(s0 - mn); s1 = __expf(s1 - mn);
            s2 = __expf(s2 - mn); s3 = __expf(s3 - mn);
            float sum = s0 + s1 + s2 + s3;
            #pragma unroll
            for (int msk = 1; msk < 16; msk <<= 1)
                sum += __shfl_xor(sum, msk);
            lrow[r] = lrow[r] * al + sum;
            mrow[r] = mn;
            alpha_r[r] = al;
            sacc[0][r] = s0; sacc[1][r] = s1; sacc[2][r] = s2; sacc[3][r] = s3;
        }
        #pragma unroll
        for (int nt = 0; nt < 8; ++nt)
            #pragma unroll
            for (int r = 0; r < 4; ++r) oacc[nt][r] *= alpha_r[r];

        // P: C-layout -> LDS -> A-layout
        #pragma unroll
        for (int jt = 0; jt < 4; ++jt)
            #pragma unroll
            for (int r = 0; r < 4; ++r)
                Ps[w][lq * 4 + r][jt * 16 + lr] = __float2bfloat16(sacc[jt][r]);
        __syncthreads();

        short8 pf[2];
        #pragma unroll
        for (int k2 = 0; k2 < 2; ++k2)
            pf[k2] = *(const short8*)(&Ps[w][lr][k2 * 32 + lq * 8]);
        #pragma unroll
        for (int k2 = 0; k2 < 2; ++k2)
            #pragma unroll
            for (int nt = 0; nt < 8; ++nt) {
                short8 vf = *(const short8*)(VsT + (nt * 16 + lr) * 64 + k2 * 32 + lq * 8);
                oacc[nt] = __builtin_amdgcn_mfma_f32_16x16x32_bf16(pf[k2], vf, oacc[nt], 0, 0, 0);
            }
    }

    // epilogue: O /= l, write bf16 [s][h*128+d]
    #pragma unroll
    for (int nt = 0; nt < 8; ++nt) {
        const int col = h * 128 + nt * 16 + lr;
        #pragma unroll
        for (int r = 0; r < 4; ++r) {
            const int s = q0 + w * 16 + lq * 4 + r;
            attnb[(size_t)s * 3072 + col] = __float2bfloat16(oacc[nt][r] / lrow[r]);
        }
    }
}

// ---------------------------------------------------------------------------
extern "C" void kernel_launch(void* const* d_in, const int* in_sizes, int n_in,
                              void* d_out, int out_size, void* d_ws, size_t ws_size,
                              hipStream_t stream)
{
    (void)in_sizes; (void)n_in; (void)out_size; (void)ws_size;
    const float* hs        = (const float*)d_in[0];
    const float* ehs       = (const float*)d_in[1];
    const float* rc        = (const float*)d_in[2];
    const float* rs        = (const float*)d_in[3];
    const float* qkv_w     = (const float*)d_in[4];
    const float* qkv_down  = (const float*)d_in[5];
    const float* qkv_up    = (const float*)d_in[6];
    const float* aqkv_w    = (const float*)d_in[7];
    const float* aqkv_down = (const float*)d_in[8];
    const float* aqkv_up   = (const float*)d_in[9];
    const float* out_w     = (const float*)d_in[10];
    const float* out_down  = (const float*)d_in[11];
    const float* out_up    = (const float*)d_in[12];
    const float* out_b     = (const float*)d_in[13];
    const float* aout_w    = (const float*)d_in[14];
    const float* aout_down = (const float*)d_in[15];
    const float* aout_up   = (const float*)d_in[16];
    const float* aout_b    = (const float*)d_in[17];
    const float* nqw  = (const float*)d_in[18];
    const float* nkw  = (const float*)d_in[19];
    const float* naqw = (const float*)d_in[20];
    const float* nakw = (const float*)d_in[21];

    char* ws = (char*)d_ws;
    size_t o = 0;
    bf16* Qb = (bf16*)(ws + o); o += (size_t)24 * 2048 * 128 * 2;
    bf16* Kb = (bf16*)(ws + o); o += (size_t)24 * 2048 * 128 * 2;
    bf16* Vb = (bf16*)(ws + o); o += (size_t)24 * 2048 * 128 * 2;  // [h][d][s]
    bf16* attnb = (bf16*)(ws + o); o += (size_t)2048 * 3072 * 2;
    bf16* Xbi = (bf16*)(ws + o); o += (size_t)1536 * 3072 * 2;
    bf16* Xbt = (bf16*)(ws + o); o += (size_t)512 * 3072 * 2;
    bf16* Wq  = (bf16*)(ws + o); o += (size_t)9216 * 3072 * 2;
    bf16* Waq = (bf16*)(ws + o); o += (size_t)9216 * 3072 * 2;
    // out-proj weights alias the QKV weight region (converted AFTER QKV GEMMs;
    // stream order guarantees the QKV GEMMs have finished reading Wq/Waq).
    bf16* Wo  = Wq;
    bf16* Wao = Wq + (size_t)3072 * 3072;
    bf16* t_img  = (bf16*)(ws + o); o += (size_t)1536 * 32 * 2;
    bf16* t_txt  = (bf16*)(ws + o); o += (size_t)512 * 32 * 2;
    bf16* t2_img = (bf16*)(ws + o); o += (size_t)1536 * 32 * 2;
    bf16* t2_txt = (bf16*)(ws + o); o += (size_t)512 * 32 * 2;
    bf16* upTq  = (bf16*)(ws + o); o += (size_t)9216 * 32 * 2;
    bf16* upTaq = (bf16*)(ws + o); o += (size_t)9216 * 32 * 2;
    bf16* upTo  = (bf16*)(ws + o); o += (size_t)3072 * 32 * 2;
    bf16* upTao = (bf16*)(ws + o); o += (size_t)3072 * 32 * 2;

    // one-time f32 -> bf16 conversions (activations + QKV weights)
    cvt_bf16<<<2304, 256, 0, stream>>>(hs, Xbi);          // 1536*3072
    cvt_bf16<<<768, 256, 0, stream>>>(ehs, Xbt);          // 512*3072
    cvt_bf16<<<13824, 256, 0, stream>>>(qkv_w, Wq);       // 9216*3072
    cvt_bf16<<<13824, 256, 0, stream>>>(aqkv_w, Waq);

    transposeR<<<144, 64, 0, stream>>>(qkv_up, upTq, 9216);
    transposeR<<<144, 64, 0, stream>>>(aqkv_up, upTaq, 9216);
    transposeR<<<48, 64, 0, stream>>>(out_up, upTo, 3072);
    transposeR<<<48, 64, 0, stream>>>(aout_up, upTao, 3072);
    downproj<<<1536, 256, 0, stream>>>(Xbi, qkv_down, t_img, 3072);
    downproj<<<512, 256, 0, stream>>>(Xbt, aqkv_down, t_txt, 3072);

    gemm128<<<dim3(72, 12), 256, 0, stream>>>(Xbi, Wq, t_img, upTq,
        nullptr, nullptr, Qb, Kb, Vb, 1536, 9216, 3072, 512, 1);
    gemm128<<<dim3(72, 4), 256, 0, stream>>>(Xbt, Waq, t_txt, upTaq,
        nullptr, nullptr, Qb, Kb, Vb, 512, 9216, 3072, 0, 1);

    // now safe to overwrite Wq/Waq region with out-proj weights
    cvt_bf16<<<4608, 256, 0, stream>>>(out_w, Wo);        // 3072*3072
    cvt_bf16<<<4608, 256, 0, stream>>>(aout_w, Wao);

    rmsrope<<<24 * 2048, 64, 0, stream>>>(Qb, Kb, rc, rs, nqw, nkw, naqw, nakw);

    attn64<<<dim3(32, 24), 256, 0, stream>>>(Qb, Kb, Vb, attnb);

    downproj<<<1536, 256, 0, stream>>>(attnb + (size_t)512 * 3072, out_down, t2_img, 3072);
    downproj<<<512, 256, 0, stream>>>(attnb, aout_down, t2_txt, 3072);

    float* outp = (float*)d_out;
    gemm128<<<dim3(24, 12), 256, 0, stream>>>(attnb + (size_t)512 * 3072, Wo,
        t2_img, upTo, out_b, outp, nullptr, nullptr, nullptr,
        1536, 3072, 3072, 0, 0);
    gemm128<<<dim3(24, 4), 256, 0, stream>>>(attnb, Wao,
        t2_txt, upTao, aout_b, outp + (size_t)1536 * 3072, nullptr, nullptr, nullptr,
        512, 3072, 3072, 0, 0);
}

// Round 2
// 1104.223 us; speedup vs baseline: 1.0592x; 1.0592x over previous
//
#include <hip/hip_runtime.h>
#include <hip/hip_bf16.h>
#include <stdint.h>

// Problem: B=1, S_IMG=1536, S_TXT=512, D=3072, H=24, HD=128, R=32.
// Harness dtypes: ALL inputs float32, output float32. Internal MFMA in bf16.
typedef __hip_bfloat16 bf16;
typedef __attribute__((ext_vector_type(8))) short short8;   // 8 bf16 (16B)
typedef __attribute__((ext_vector_type(4))) short short4b;  // 4 bf16 (8B)
typedef __attribute__((ext_vector_type(4))) float floatx4;  // MFMA C/D

__device__ __forceinline__ short bfs(float x) {
    // RNE f32 -> bf16, returned as raw bits
    uint32_t u = __builtin_bit_cast(uint32_t, x);
    u += 0x7FFFu + ((u >> 16) & 1u);
    return (short)(u >> 16);
}
__device__ __forceinline__ float b2f(bf16 x) { return __bfloat162float(x); }

// async global->LDS, 16B per lane. LDS dest is wave-uniform base + lane*16,
// so per-lane dest pointers must be exactly base + lane*16 (linear layout).
__device__ __forceinline__ void load_lds16(const bf16* g, bf16* l) {
    __builtin_amdgcn_global_load_lds(
        (const __attribute__((address_space(1))) uint32_t*)g,
        (__attribute__((address_space(3))) uint32_t*)l, 16, 0, 0);
}

// ---------------------------------------------------------------------------
// f32 -> bf16 bulk convert. 8 elems/thread, grid = n/2048 blocks.
__global__ __launch_bounds__(256) void cvt_bf16(const float* __restrict__ X,
                                                bf16* __restrict__ Y) {
    const size_t i = ((size_t)blockIdx.x * 256 + threadIdx.x) * 8;
    const float4 v0 = *(const float4*)(X + i);
    const float4 v1 = *(const float4*)(X + i + 4);
    short8 o = { bfs(v0.x), bfs(v0.y), bfs(v0.z), bfs(v0.w),
                 bfs(v1.x), bfs(v1.y), bfs(v1.z), bfs(v1.w) };
    *(short8*)(Y + i) = o;
}

// ---------------------------------------------------------------------------
// upT[n][r] = up[r][n]   (up is [32][N] row-major f32 -> bf16)
__global__ __launch_bounds__(64) void transposeR(const float* __restrict__ U,
                                                 bf16* __restrict__ UT, int N) {
    const int n = blockIdx.x * 64 + threadIdx.x;
    #pragma unroll
    for (int r = 0; r < 32; ++r)
        UT[(size_t)n * 32 + r] = __float2bfloat16(U[(size_t)r * N + n]);
}

// ---------------------------------------------------------------------------
// t[m][r] = sum_k x[m][k] * down[k][r]   (K=3072, R=32). One block per row m.
// x is bf16, down is f32, t written bf16.
__global__ __launch_bounds__(256) void downproj(const bf16* __restrict__ X,
                                                const float* __restrict__ Dn,
                                                bf16* __restrict__ T, int K) {
    const int m = blockIdx.x;
    const int n = threadIdx.x & 31;
    const int kg = threadIdx.x >> 5;           // 8 K-groups
    const bf16* x = X + (size_t)m * K;
    const int kc = K >> 3;                     // 384
    float acc = 0.f;
    #pragma unroll 4
    for (int k = kg * kc; k < (kg + 1) * kc; ++k)
        acc += b2f(x[k]) * Dn[(size_t)k * 32 + n];
    __shared__ float red[8][32];
    red[kg][n] = acc;
    __syncthreads();
    if (threadIdx.x < 32) {
        float s = 0.f;
        #pragma unroll
        for (int g = 0; g < 8; ++g) s += red[g][n];
        T[(size_t)m * 32 + n] = __float2bfloat16(s);
    }
}

// ---------------------------------------------------------------------------
// C = A @ B^T + t @ upT^T (+bias). A:[M][K], B:[N][K], t:[M][32], upT:[N][32],
// ALL bf16 in global. Staged to LDS via global_load_lds (no VALU in staging).
// Low-rank term is one extra K-step. mode 0: write C row-major [M][N] f32.
// mode 1: scatter to Q[h][s][128], K[h][s][128], V[h][128][s] (bf16).
__global__ __launch_bounds__(256) void gemm128(
    const bf16* __restrict__ A, const bf16* __restrict__ B,
    const bf16* __restrict__ T, const bf16* __restrict__ UpT,
    const float* __restrict__ bias, float* __restrict__ C,
    bf16* __restrict__ Qb, bf16* __restrict__ Kb, bf16* __restrict__ Vb,
    int M, int N, int K, int s_base, int mode)
{
    __shared__ __align__(16) bf16 As[128 * 32];
    __shared__ __align__(16) bf16 Bs[128 * 32];
    const int tid = threadIdx.x;
    const int lane = tid & 63, w = tid >> 6;
    const int wm = (w >> 1) * 64, wn = (w & 1) * 64;
    const int lr = lane & 15, lq = lane >> 4;

    // XCD-aware bijective swizzle (all grids here have nwg % 8 == 0)
    int bid = blockIdx.y * gridDim.x + blockIdx.x;
    const int cpx = (gridDim.x * gridDim.y) >> 3;
    bid = (bid & 7) * cpx + (bid >> 3);
    const int by = bid / gridDim.x, bx = bid - by * gridDim.x;
    const int m0 = by * 128, n0 = bx * 128;

    floatx4 acc[4][4] = {};
    const int ksteps = K >> 5;
    for (int kt = 0; kt <= ksteps; ++kt) {
        const bf16 *a_src, *b_src;
        int lda, ldb;
        if (kt < ksteps) {
            a_src = A + (size_t)m0 * K + kt * 32; lda = K;
            b_src = B + (size_t)n0 * K + kt * 32; ldb = K;
        } else {                                  // low-rank K-step
            a_src = T   + (size_t)m0 * 32; lda = 32;
            b_src = UpT + (size_t)n0 * 32; ldb = 32;
        }
        __syncthreads();
        // stage: 128 rows x 32 bf16 = 512 chunks of 16B per matrix
        #pragma unroll
        for (int it = 0; it < 2; ++it) {
            const int c = tid + it * 256;
            const int row = c >> 2, sub = c & 3;
            load_lds16(a_src + (size_t)row * lda + sub * 8, As + c * 8);
        }
        #pragma unroll
        for (int it = 0; it < 2; ++it) {
            const int c = tid + it * 256;
            const int row = c >> 2, sub = c & 3;
            load_lds16(b_src + (size_t)row * ldb + sub * 8, Bs + c * 8);
        }
        __syncthreads();
        short8 af[4], bfr[4];
        #pragma unroll
        for (int i = 0; i < 4; ++i)
            af[i] = *(const short8*)(As + (wm + i * 16 + lr) * 32 + lq * 8);
        #pragma unroll
        for (int j = 0; j < 4; ++j)
            bfr[j] = *(const short8*)(Bs + (wn + j * 16 + lr) * 32 + lq * 8);
        #pragma unroll
        for (int i = 0; i < 4; ++i)
            #pragma unroll
            for (int j = 0; j < 4; ++j)
                acc[i][j] = __builtin_amdgcn_mfma_f32_16x16x32_bf16(
                    af[i], bfr[j], acc[i][j], 0, 0, 0);
    }

    if (mode == 0) {
        #pragma unroll
        for (int j = 0; j < 4; ++j) {
            const int col = n0 + wn + j * 16 + lr;
            const float bv = bias ? bias[col] : 0.0f;
            #pragma unroll
            for (int i = 0; i < 4; ++i) {
                const int rowb = m0 + wm + i * 16 + lq * 4;
                #pragma unroll
                for (int r = 0; r < 4; ++r)
                    C[(size_t)(rowb + r) * N + col] = acc[i][j][r] + bv;
            }
        }
    } else {
        #pragma unroll
        for (int j = 0; j < 4; ++j) {
            const int col = n0 + wn + j * 16 + lr;
            const int which = col / 3072;           // uniform per block (128 | 3072)
            const int cc = col - which * 3072;
            const int hh = cc >> 7, dd = cc & 127;
            #pragma unroll
            for (int i = 0; i < 4; ++i) {
                const int rowb = m0 + wm + i * 16 + lq * 4;
                const int s0 = s_base + rowb;
                if (which == 2) {
                    // V^T: 4 consecutive s per lane -> one 8B store
                    short4b pv = { bfs(acc[i][j][0]), bfs(acc[i][j][1]),
                                   bfs(acc[i][j][2]), bfs(acc[i][j][3]) };
                    *(short4b*)(Vb + ((size_t)hh * 128 + dd) * 2048 + s0) = pv;
                } else {
                    bf16* dst = (which == 0 ? Qb : Kb)
                              + ((size_t)hh * 2048 + s0) * 128 + dd;
                    #pragma unroll
                    for (int r = 0; r < 4; ++r)
                        dst[(size_t)r * 128] = __float2bfloat16(acc[i][j][r]);
                }
            }
        }
    }
}

// ---------------------------------------------------------------------------
// RMSNorm (per (s,h) row of 128) + RoPE, in-place on Q and K (bf16 buffers).
// cos/sin/norm-weights are f32 inputs. 1 wave/block.
__global__ __launch_bounds__(64) void rmsrope(
    bf16* __restrict__ Qb, bf16* __restrict__ Kb,
    const float* __restrict__ cosb, const float* __restrict__ sinb,
    const float* __restrict__ nqw, const float* __restrict__ nkw,
    const float* __restrict__ naqw, const float* __restrict__ nakw)
{
    const int s = blockIdx.x & 2047;
    const int h = blockIdx.x >> 11;
    const int i = threadIdx.x;                       // pair index 0..63
    const float c  = cosb[s * 64 + i];
    const float sn = sinb[s * 64 + i];
    const bool txt = (s < 512);
    const size_t base = ((size_t)h * 2048 + s) * 128;

    {
        __hip_bfloat162* row = (__hip_bfloat162*)(Qb + base);
        __hip_bfloat162 pv = row[i];
        float x0 = b2f(pv.x), x1 = b2f(pv.y);
        float ss = x0 * x0 + x1 * x1;
        #pragma unroll
        for (int m = 1; m < 64; m <<= 1) ss += __shfl_xor(ss, m);
        const float rms = rsqrtf(ss * (1.0f / 128.0f) + 1e-5f);
        const float* nw = txt ? naqw : nqw;
        const float y0 = x0 * rms * nw[2 * i];
        const float y1 = x1 * rms * nw[2 * i + 1];
        __hip_bfloat162 o;
        o.x = __float2bfloat16(y0 * c - y1 * sn);
        o.y = __float2bfloat16(y0 * sn + y1 * c);
        row[i] = o;
    }
    {
        __hip_bfloat162* row = (__hip_bfloat162*)(Kb + base);
        __hip_bfloat162 pv = row[i];
        float x0 = b2f(pv.x), x1 = b2f(pv.y);
        float ss = x0 * x0 + x1 * x1;
        #pragma unroll
        for (int m = 1; m < 64; m <<= 1) ss += __shfl_xor(ss, m);
        const float rms = rsqrtf(ss * (1.0f / 128.0f) + 1e-5f);
        const float* nw = txt ? nakw : nkw;
        const float y0 = x0 * rms * nw[2 * i];
        const float y1 = x1 * rms * nw[2 * i + 1];
        __hip_bfloat162 o;
        o.x = __float2bfloat16(y0 * c - y1 * sn);
        o.y = __float2bfloat16(y0 * sn + y1 * c);
        row[i] = o;
    }
}

// ---------------------------------------------------------------------------
// Flash attention: block = 64 q-rows of one head; KV tiles of 64; 4 waves,
// each wave owns 16 q-rows x full HD=128. Online softmax in registers.
// Output attnb is bf16 [s][3072]. K/V staged via global_load_lds with the
// 16B-chunk XOR swizzle (chunk ^= row&7) applied to the GLOBAL source (LDS
// dest must stay linear) and to every ds_read address — this removes the
// 16-way bank conflicts of the 256B/128B row strides (rule #21 / T2).
__global__ __launch_bounds__(256) void attn64(
    const bf16* __restrict__ Qb, const bf16* __restrict__ Kb,
    const bf16* __restrict__ Vb, bf16* __restrict__ attnb)
{
    __shared__ __align__(16) bf16 Ks[64 * 128];     // [kv][d], swizzled
    __shared__ __align__(16) bf16 VsT[128 * 64];    // [d][kv], swizzled
    __shared__ __align__(16) bf16 Ps[4][16 * 64];   // per-wave P, swizzled
    const int tid = threadIdx.x, lane = tid & 63, w = tid >> 6;
    const int lr = lane & 15, lq = lane >> 4;
    const int h = blockIdx.y, q0 = blockIdx.x * 64;
    const float scale = 0.08838834764831845f;   // 1/sqrt(128)

    // Q fragments for this wave's 16 rows (kept in registers whole kernel)
    const bf16* qrow = Qb + ((size_t)h * 2048 + q0 + w * 16 + lr) * 128;
    short8 qf[4];
    #pragma unroll
    for (int ks = 0; ks < 4; ++ks)
        qf[ks] = *(const short8*)(qrow + ks * 32 + lq * 8);

    floatx4 oacc[8] = {};
    float mrow[4] = {-1e30f, -1e30f, -1e30f, -1e30f};
    float lrow[4] = {0.f, 0.f, 0.f, 0.f};

    for (int kt = 0; kt < 32; ++kt) {
        const int kv0 = kt * 64;
        __syncthreads();
        // Ks: 64 rows x 16 chunks of 16B; source chunk pre-swizzled
        #pragma unroll
        for (int it = 0; it < 4; ++it) {
            const int c = tid + it * 256;
            const int row = c >> 4, cg = (c & 15) ^ (row & 7);
            load_lds16(Kb + ((size_t)h * 2048 + kv0 + row) * 128 + cg * 8,
                       Ks + c * 8);
        }
        // VsT: 128 rows x 8 chunks of 16B; source chunk pre-swizzled
        #pragma unroll
        for (int it = 0; it < 4; ++it) {
            const int c = tid + it * 256;
            const int row = c >> 3, cg = (c & 7) ^ (row & 7);
            load_lds16(Vb + ((size_t)h * 128 + row) * 2048 + kv0 + cg * 8,
                       VsT + c * 8);
        }
        __syncthreads();

        // S = Q K^T for 16 q x 64 kv
        floatx4 sacc[4] = {};
        __builtin_amdgcn_s_setprio(1);
        #pragma unroll
        for (int ks = 0; ks < 4; ++ks)
            #pragma unroll
            for (int jt = 0; jt < 4; ++jt) {
                const int row = jt * 16 + lr;
                short8 kf = *(const short8*)(
                    Ks + row * 128 + (((ks * 4 + lq) ^ (row & 7)) * 8));
                sacc[jt] = __builtin_amdgcn_mfma_f32_16x16x32_bf16(qf[ks], kf, sacc[jt], 0, 0, 0);
            }
        __builtin_amdgcn_s_setprio(0);

        // online softmax (lane holds rows lq*4+r, col lr of each 16-block)
        float alpha_r[4];
        #pragma unroll
        for (int r = 0; r < 4; ++r) {
            float s0 = sacc[0][r] * scale, s1 = sacc[1][r] * scale;
            float s2 = sacc[2][r] * scale, s3 = sacc[3][r] * scale;
            float mx = fmaxf(fmaxf(s0, s1), fmaxf(s2, s3));
            #pragma unroll
            for (int msk = 1; msk < 16; msk <<= 1)
                mx = fmaxf(mx, __shfl_xor(mx, msk));
            const float mn = fmaxf(mrow[r], mx);
            const float al = __expf(mrow[r] - mn);
            s0 = __expf(s0 - mn); s1 = __expf(s1 - mn);
            s2 = __expf(s2 - mn); s3 = __expf(s3 - mn);
            float sum = s0 + s1 + s2 + s3;
            #pragma unroll
            for (int msk = 1; msk < 16; msk <<= 1)
                sum += __shfl_xor(sum, msk);
            lrow[r] = lrow[r] * al + sum;
            mrow[r] = mn;
            alpha_r[r] = al;
            sacc[0][r] = s0; sacc[1][r] = s1; sacc[2][r] = s2; sacc[3][r] = s3;
        }
        #pragma unroll
        for (int nt = 0; nt < 8; ++nt)
            #pragma unroll
            for (int r = 0; r < 4; ++r) oacc[nt][r] *= alpha_r[r];

        // P: C-layout -> LDS (wave-private, swizzled) -> A-layout
        #pragma unroll
        for (int jt = 0; jt < 4; ++jt)
            #pragma unroll
            for (int r = 0; r < 4; ++r) {
                const int q = lq * 4 + r;
                const int ir = jt * 16 + lr;
                Ps[w][q * 64 + ((((ir >> 3) ^ (q & 7))) << 3) + (ir & 7)] =
                    __float2bfloat16(sacc[jt][r]);
            }
        // no barrier: Ps[w] is wave-private; same-wave DS ops are ordered

        short8 pf[2];
        #pragma unroll
        for (int k2 = 0; k2 < 2; ++k2)
            pf[k2] = *(const short8*)(
                &Ps[w][lr * 64 + (((k2 * 4 + lq) ^ (lr & 7)) << 3)]);
        __builtin_amdgcn_s_setprio(1);
        #pragma unroll
        for (int k2 = 0; k2 < 2; ++k2)
            #pragma unroll
            for (int nt = 0; nt < 8; ++nt) {
                const int row = nt * 16 + lr;
                short8 vf = *(const short8*)(
                    VsT + row * 64 + (((k2 * 4 + lq) ^ (row & 7)) * 8));
                oacc[nt] = __builtin_amdgcn_mfma_f32_16x16x32_bf16(pf[k2], vf, oacc[nt], 0, 0, 0);
            }
        __builtin_amdgcn_s_setprio(0);
    }

    // epilogue: O /= l (4 reciprocals), write bf16 [s][h*128+d]
    float rl[4];
    #pragma unroll
    for (int r = 0; r < 4; ++r) rl[r] = 1.0f / lrow[r];
    #pragma unroll
    for (int nt = 0; nt < 8; ++nt) {
        const int col = h * 128 + nt * 16 + lr;
        #pragma unroll
        for (int r = 0; r < 4; ++r) {
            const int s = q0 + w * 16 + lq * 4 + r;
            attnb[(size_t)s * 3072 + col] = __float2bfloat16(oacc[nt][r] * rl[r]);
        }
    }
}

// ---------------------------------------------------------------------------
extern "C" void kernel_launch(void* const* d_in, const int* in_sizes, int n_in,
                              void* d_out, int out_size, void* d_ws, size_t ws_size,
                              hipStream_t stream)
{
    (void)in_sizes; (void)n_in; (void)out_size; (void)ws_size;
    const float* hs        = (const float*)d_in[0];
    const float* ehs       = (const float*)d_in[1];
    const float* rc        = (const float*)d_in[2];
    const float* rs        = (const float*)d_in[3];
    const float* qkv_w     = (const float*)d_in[4];
    const float* qkv_down  = (const float*)d_in[5];
    const float* qkv_up    = (const float*)d_in[6];
    const float* aqkv_w    = (const float*)d_in[7];
    const float* aqkv_down = (const float*)d_in[8];
    const float* aqkv_up   = (const float*)d_in[9];
    const float* out_w     = (const float*)d_in[10];
    const float* out_down  = (const float*)d_in[11];
    const float* out_up    = (const float*)d_in[12];
    const float* out_b     = (const float*)d_in[13];
    const float* aout_w    = (const float*)d_in[14];
    const float* aout_down = (const float*)d_in[15];
    const float* aout_up   = (const float*)d_in[16];
    const float* aout_b    = (const float*)d_in[17];
    const float* nqw  = (const float*)d_in[18];
    const float* nkw  = (const float*)d_in[19];
    const float* naqw = (const float*)d_in[20];
    const float* nakw = (const float*)d_in[21];

    char* ws = (char*)d_ws;
    size_t o = 0;
    bf16* Qb = (bf16*)(ws + o); o += (size_t)24 * 2048 * 128 * 2;
    bf16* Kb = (bf16*)(ws + o); o += (size_t)24 * 2048 * 128 * 2;
    bf16* Vb = (bf16*)(ws + o); o += (size_t)24 * 2048 * 128 * 2;  // [h][d][s]
    bf16* attnb = (bf16*)(ws + o); o += (size_t)2048 * 3072 * 2;
    bf16* Xbi = (bf16*)(ws + o); o += (size_t)1536 * 3072 * 2;
    bf16* Xbt = (bf16*)(ws + o); o += (size_t)512 * 3072 * 2;
    bf16* Wq  = (bf16*)(ws + o); o += (size_t)9216 * 3072 * 2;
    bf16* Waq = (bf16*)(ws + o); o += (size_t)9216 * 3072 * 2;
    // out-proj weights alias the QKV weight region (converted AFTER QKV GEMMs;
    // stream order guarantees the QKV GEMMs have finished reading Wq/Waq).
    bf16* Wo  = Wq;
    bf16* Wao = Wq + (size_t)3072 * 3072;
    bf16* t_img  = (bf16*)(ws + o); o += (size_t)1536 * 32 * 2;
    bf16* t_txt  = (bf16*)(ws + o); o += (size_t)512 * 32 * 2;
    bf16* t2_img = (bf16*)(ws + o); o += (size_t)1536 * 32 * 2;
    bf16* t2_txt = (bf16*)(ws + o); o += (size_t)512 * 32 * 2;
    bf16* upTq  = (bf16*)(ws + o); o += (size_t)9216 * 32 * 2;
    bf16* upTaq = (bf16*)(ws + o); o += (size_t)9216 * 32 * 2;
    bf16* upTo  = (bf16*)(ws + o); o += (size_t)3072 * 32 * 2;
    bf16* upTao = (bf16*)(ws + o); o += (size_t)3072 * 32 * 2;

    // one-time f32 -> bf16 conversions (activations + QKV weights)
    cvt_bf16<<<2304, 256, 0, stream>>>(hs, Xbi);          // 1536*3072
    cvt_bf16<<<768, 256, 0, stream>>>(ehs, Xbt);          // 512*3072
    cvt_bf16<<<13824, 256, 0, stream>>>(qkv_w, Wq);       // 9216*3072
    cvt_bf16<<<13824, 256, 0, stream>>>(aqkv_w, Waq);

    transposeR<<<144, 64, 0, stream>>>(qkv_up, upTq, 9216);
    transposeR<<<144, 64, 0, stream>>>(aqkv_up, upTaq, 9216);
    transposeR<<<48, 64, 0, stream>>>(out_up, upTo, 3072);
    transposeR<<<48, 64, 0, stream>>>(aout_up, upTao, 3072);
    downproj<<<1536, 256, 0, stream>>>(Xbi, qkv_down, t_img, 3072);
    downproj<<<512, 256, 0, stream>>>(Xbt, aqkv_down, t_txt, 3072);

    gemm128<<<dim3(72, 12), 256, 0, stream>>>(Xbi, Wq, t_img, upTq,
        nullptr, nullptr, Qb, Kb, Vb, 1536, 9216, 3072, 512, 1);
    gemm128<<<dim3(72, 4), 256, 0, stream>>>(Xbt, Waq, t_txt, upTaq,
        nullptr, nullptr, Qb, Kb, Vb, 512, 9216, 3072, 0, 1);

    // now safe to overwrite Wq/Waq region with out-proj weights
    cvt_bf16<<<4608, 256, 0, stream>>>(out_w, Wo);        // 3072*3072
    cvt_bf16<<<4608, 256, 0, stream>>>(aout_w, Wao);

    rmsrope<<<24 * 2048, 64, 0, stream>>>(Qb, Kb, rc, rs, nqw, nkw, naqw, nakw);

    attn64<<<dim3(32, 24), 256, 0, stream>>>(Qb, Kb, Vb, attnb);

    downproj<<<1536, 256, 0, stream>>>(attnb + (size_t)512 * 3072, out_down, t2_img, 3072);
    downproj<<<512, 256, 0, stream>>>(attnb, aout_down, t2_txt, 3072);

    float* outp = (float*)d_out;
    gemm128<<<dim3(24, 12), 256, 0, stream>>>(attnb + (size_t)512 * 3072, Wo,
        t2_img, upTo, out_b, outp, nullptr, nullptr, nullptr,
        1536, 3072, 3072, 0, 0);
    gemm128<<<dim3(24, 4), 256, 0, stream>>>(attnb, Wao,
        t2_txt, upTao, aout_b, outp + (size_t)1536 * 3072, nullptr, nullptr, nullptr,
        512, 3072, 3072, 0, 0);
}

// Round 3
// 953.949 us; speedup vs baseline: 1.2261x; 1.1575x over previous
//
#include <hip/hip_runtime.h>
#include <hip/hip_bf16.h>
#include <stdint.h>

// Problem: B=1, S_IMG=1536, S_TXT=512, D=3072, H=24, HD=128, R=32.
// Harness dtypes: ALL inputs float32, output float32. Internal MFMA in bf16.
typedef __hip_bfloat16 bf16;
typedef __attribute__((ext_vector_type(8))) short short8;   // 8 bf16 (16B)
typedef __attribute__((ext_vector_type(4))) short short4b;  // 4 bf16 (8B)
typedef __attribute__((ext_vector_type(4))) float floatx4;  // MFMA C/D

__device__ __forceinline__ short bfs(float x) {
    // RNE f32 -> bf16, returned as raw bits
    uint32_t u = __builtin_bit_cast(uint32_t, x);
    u += 0x7FFFu + ((u >> 16) & 1u);
    return (short)(u >> 16);
}
__device__ __forceinline__ float b2f(bf16 x) { return __bfloat162float(x); }

// async global->LDS, 16B per lane. LDS dest is wave-uniform base + lane*16,
// so per-lane dest pointers must be exactly base + lane*16 (linear layout).
__device__ __forceinline__ void load_lds16(const bf16* g, bf16* l) {
    __builtin_amdgcn_global_load_lds(
        (const __attribute__((address_space(1))) uint32_t*)g,
        (__attribute__((address_space(3))) uint32_t*)l, 16, 0, 0);
}

// ---------------------------------------------------------------------------
// f32 -> bf16 bulk convert. 8 elems/thread, grid = n/2048 blocks.
__global__ __launch_bounds__(256) void cvt_bf16(const float* __restrict__ X,
                                                bf16* __restrict__ Y) {
    const size_t i = ((size_t)blockIdx.x * 256 + threadIdx.x) * 8;
    const float4 v0 = *(const float4*)(X + i);
    const float4 v1 = *(const float4*)(X + i + 4);
    short8 o = { bfs(v0.x), bfs(v0.y), bfs(v0.z), bfs(v0.w),
                 bfs(v1.x), bfs(v1.y), bfs(v1.z), bfs(v1.w) };
    *(short8*)(Y + i) = o;
}

// ---------------------------------------------------------------------------
// upT[n][r] = up[r][n]   (up is [32][N] row-major f32 -> bf16)
__global__ __launch_bounds__(64) void transposeR(const float* __restrict__ U,
                                                 bf16* __restrict__ UT, int N) {
    const int n = blockIdx.x * 64 + threadIdx.x;
    #pragma unroll
    for (int r = 0; r < 32; ++r)
        UT[(size_t)n * 32 + r] = __float2bfloat16(U[(size_t)r * N + n]);
}

// ---------------------------------------------------------------------------
// t[m][r] = sum_k x[m][k] * down[k][r]   (K=3072, R=32). One block per row m.
// x is bf16, down is f32, t written bf16.
__global__ __launch_bounds__(256) void downproj(const bf16* __restrict__ X,
                                                const float* __restrict__ Dn,
                                                bf16* __restrict__ T, int K) {
    const int m = blockIdx.x;
    const int n = threadIdx.x & 31;
    const int kg = threadIdx.x >> 5;           // 8 K-groups
    const bf16* x = X + (size_t)m * K;
    const int kc = K >> 3;                     // 384
    float acc = 0.f;
    #pragma unroll 4
    for (int k = kg * kc; k < (kg + 1) * kc; ++k)
        acc += b2f(x[k]) * Dn[(size_t)k * 32 + n];
    __shared__ float red[8][32];
    red[kg][n] = acc;
    __syncthreads();
    if (threadIdx.x < 32) {
        float s = 0.f;
        #pragma unroll
        for (int g = 0; g < 8; ++g) s += red[g][n];
        T[(size_t)m * 32 + n] = __float2bfloat16(s);
    }
}

// ---------------------------------------------------------------------------
// Two fused GEMMs in one dispatch (set 0 = img, set 1 = txt), selected by
// m-tile index: by < mtiles0 -> set 0, else set 1.
// C = A @ B^T + t @ upT^T (+bias). A:[M][K], B:[N][K], t:[M][32], upT:[N][32],
// ALL bf16. 2-phase double-buffered K-loop: issue next-tile global_load_lds
// BEFORE ds_read+MFMA of current tile; one __syncthreads (vmcnt0+barrier)
// per K-step -> HBM/L2 latency hides under compute (T3 minimum recipe).
// mode 0: write C row-major f32. mode 1: scatter Q/K [h][s][128], V^T [h][128][s].
__global__ __launch_bounds__(256) void gemm128(
    const bf16* __restrict__ A0, const bf16* __restrict__ B0,
    const bf16* __restrict__ T0, const bf16* __restrict__ U0,
    const bf16* __restrict__ A1, const bf16* __restrict__ B1,
    const bf16* __restrict__ T1, const bf16* __restrict__ U1,
    const float* __restrict__ bias0, const float* __restrict__ bias1,
    float* __restrict__ C0, float* __restrict__ C1,
    bf16* __restrict__ Qb, bf16* __restrict__ Kb, bf16* __restrict__ Vb,
    int mtiles0, int N, int K, int sb0, int sb1, int mode)
{
    __shared__ __align__(16) bf16 As[2][128 * 32];
    __shared__ __align__(16) bf16 Bs[2][128 * 32];
    const int tid = threadIdx.x;
    const int lane = tid & 63, w = tid >> 6;
    const int wm = (w >> 1) * 64, wn = (w & 1) * 64;
    const int lr = lane & 15, lq = lane >> 4;

    // XCD-aware bijective swizzle (all grids here have nwg % 8 == 0)
    int bid = blockIdx.y * gridDim.x + blockIdx.x;
    const int cpx = (gridDim.x * gridDim.y) >> 3;
    bid = (bid & 7) * cpx + (bid >> 3);
    const int by = bid / gridDim.x, bx = bid - by * gridDim.x;

    const bool set1 = (by >= mtiles0);
    const int lby = set1 ? (by - mtiles0) : by;
    const int m0 = lby * 128, n0 = bx * 128;
    const bf16* Asel = set1 ? A1 : A0;
    const bf16* Bsel = set1 ? B1 : B0;
    const bf16* Tsel = set1 ? T1 : T0;
    const bf16* Usel = set1 ? U1 : U0;
    const int s_base = set1 ? sb1 : sb0;

    const int ksteps = K >> 5;                    // full K-steps; +1 low-rank

    // stage K-step kt into buffer buf (512 x 16B per matrix, 2 iters/thread)
    auto stage = [&](int buf, int kt) {
        const bf16 *a_src, *b_src;
        int lda, ldb;
        if (kt < ksteps) {
            a_src = Asel + (size_t)m0 * K + kt * 32; lda = K;
            b_src = Bsel + (size_t)n0 * K + kt * 32; ldb = K;
        } else {                                  // low-rank K-step
            a_src = Tsel + (size_t)m0 * 32; lda = 32;
            b_src = Usel + (size_t)n0 * 32; ldb = 32;
        }
        bf16* Ad = &As[buf][0];
        bf16* Bd = &Bs[buf][0];
        #pragma unroll
        for (int it = 0; it < 2; ++it) {
            const int c = tid + it * 256;
            const int row = c >> 2, sub = c & 3;
            load_lds16(a_src + (size_t)row * lda + sub * 8, Ad + c * 8);
        }
        #pragma unroll
        for (int it = 0; it < 2; ++it) {
            const int c = tid + it * 256;
            const int row = c >> 2, sub = c & 3;
            load_lds16(b_src + (size_t)row * ldb + sub * 8, Bd + c * 8);
        }
    };

    floatx4 acc[4][4] = {};
    stage(0, 0);
    __syncthreads();                               // vmcnt(0) + barrier
    int cur = 0;
    for (int kt = 0; kt <= ksteps; ++kt) {
        if (kt < ksteps) stage(cur ^ 1, kt + 1);   // prefetch next tile
        const bf16* Ac = &As[cur][0];
        const bf16* Bc = &Bs[cur][0];
        short8 af[4], bfr[4];
        #pragma unroll
        for (int i = 0; i < 4; ++i)
            af[i] = *(const short8*)(Ac + (wm + i * 16 + lr) * 32 + lq * 8);
        #pragma unroll
        for (int j = 0; j < 4; ++j)
            bfr[j] = *(const short8*)(Bc + (wn + j * 16 + lr) * 32 + lq * 8);
        #pragma unroll
        for (int i = 0; i < 4; ++i)
            #pragma unroll
            for (int j = 0; j < 4; ++j)
                acc[i][j] = __builtin_amdgcn_mfma_f32_16x16x32_bf16(
                    af[i], bfr[j], acc[i][j], 0, 0, 0);
        __syncthreads();                           // drains prefetch, syncs bufs
        cur ^= 1;
    }

    if (mode == 0) {
        float* Csel = set1 ? C1 : C0;
        const float* bsel = set1 ? bias1 : bias0;
        #pragma unroll
        for (int j = 0; j < 4; ++j) {
            const int col = n0 + wn + j * 16 + lr;
            const float bv = bsel ? bsel[col] : 0.0f;
            #pragma unroll
            for (int i = 0; i < 4; ++i) {
                const int rowb = m0 + wm + i * 16 + lq * 4;
                #pragma unroll
                for (int r = 0; r < 4; ++r)
                    Csel[(size_t)(rowb + r) * N + col] = acc[i][j][r] + bv;
            }
        }
    } else {
        #pragma unroll
        for (int j = 0; j < 4; ++j) {
            const int col = n0 + wn + j * 16 + lr;
            const int which = col / 3072;           // uniform per block (128 | 3072)
            const int cc = col - which * 3072;
            const int hh = cc >> 7, dd = cc & 127;
            #pragma unroll
            for (int i = 0; i < 4; ++i) {
                const int rowb = m0 + wm + i * 16 + lq * 4;
                const int s0 = s_base + rowb;
                if (which == 2) {
                    // V^T: 4 consecutive s per lane -> one 8B store
                    short4b pv = { bfs(acc[i][j][0]), bfs(acc[i][j][1]),
                                   bfs(acc[i][j][2]), bfs(acc[i][j][3]) };
                    *(short4b*)(Vb + ((size_t)hh * 128 + dd) * 2048 + s0) = pv;
                } else {
                    bf16* dst = (which == 0 ? Qb : Kb)
                              + ((size_t)hh * 2048 + s0) * 128 + dd;
                    #pragma unroll
                    for (int r = 0; r < 4; ++r)
                        dst[(size_t)r * 128] = __float2bfloat16(acc[i][j][r]);
                }
            }
        }
    }
}

// ---------------------------------------------------------------------------
// RMSNorm (per (s,h) row of 128) + RoPE, in-place on Q and K (bf16 buffers).
// 4 rows per block (one per wave), 256 threads.
__global__ __launch_bounds__(256) void rmsrope(
    bf16* __restrict__ Qb, bf16* __restrict__ Kb,
    const float* __restrict__ cosb, const float* __restrict__ sinb,
    const float* __restrict__ nqw, const float* __restrict__ nkw,
    const float* __restrict__ naqw, const float* __restrict__ nakw)
{
    const int idx = blockIdx.x * 4 + (threadIdx.x >> 6);
    const int i = threadIdx.x & 63;                  // pair index 0..63
    const int s = idx & 2047;
    const int h = idx >> 11;
    const float c  = cosb[s * 64 + i];
    const float sn = sinb[s * 64 + i];
    const bool txt = (s < 512);
    const size_t base = ((size_t)h * 2048 + s) * 128;

    {
        __hip_bfloat162* row = (__hip_bfloat162*)(Qb + base);
        __hip_bfloat162 pv = row[i];
        float x0 = b2f(pv.x), x1 = b2f(pv.y);
        float ss = x0 * x0 + x1 * x1;
        #pragma unroll
        for (int m = 1; m < 64; m <<= 1) ss += __shfl_xor(ss, m);
        const float rms = rsqrtf(ss * (1.0f / 128.0f) + 1e-5f);
        const float2 nw = *(const float2*)((txt ? naqw : nqw) + 2 * i);
        const float y0 = x0 * rms * nw.x;
        const float y1 = x1 * rms * nw.y;
        __hip_bfloat162 o;
        o.x = __float2bfloat16(y0 * c - y1 * sn);
        o.y = __float2bfloat16(y0 * sn + y1 * c);
        row[i] = o;
    }
    {
        __hip_bfloat162* row = (__hip_bfloat162*)(Kb + base);
        __hip_bfloat162 pv = row[i];
        float x0 = b2f(pv.x), x1 = b2f(pv.y);
        float ss = x0 * x0 + x1 * x1;
        #pragma unroll
        for (int m = 1; m < 64; m <<= 1) ss += __shfl_xor(ss, m);
        const float rms = rsqrtf(ss * (1.0f / 128.0f) + 1e-5f);
        const float2 nw = *(const float2*)((txt ? nakw : nkw) + 2 * i);
        const float y0 = x0 * rms * nw.x;
        const float y1 = x1 * rms * nw.y;
        __hip_bfloat162 o;
        o.x = __float2bfloat16(y0 * c - y1 * sn);
        o.y = __float2bfloat16(y0 * sn + y1 * c);
        row[i] = o;
    }
}

// ---------------------------------------------------------------------------
// Flash attention: block = 64 q-rows of one head; KV tiles of 64; 4 waves,
// each wave owns 16 q-rows x full HD=128. Online softmax in registers.
// Output attnb is bf16 [s][3072]. K/V staged via global_load_lds with the
// 16B-chunk XOR swizzle (chunk ^= row&7) applied to the GLOBAL source (LDS
// dest must stay linear) and to every ds_read address — this removes the
// 16-way bank conflicts of the 256B/128B row strides (rule #21 / T2).
__global__ __launch_bounds__(256) void attn64(
    const bf16* __restrict__ Qb, const bf16* __restrict__ Kb,
    const bf16* __restrict__ Vb, bf16* __restrict__ attnb)
{
    __shared__ __align__(16) bf16 Ks[64 * 128];     // [kv][d], swizzled
    __shared__ __align__(16) bf16 VsT[128 * 64];    // [d][kv], swizzled
    __shared__ __align__(16) bf16 Ps[4][16 * 64];   // per-wave P, swizzled
    const int tid = threadIdx.x, lane = tid & 63, w = tid >> 6;
    const int lr = lane & 15, lq = lane >> 4;
    const int h = blockIdx.y, q0 = blockIdx.x * 64;
    const float scale = 0.08838834764831845f;   // 1/sqrt(128)

    // Q fragments for this wave's 16 rows (kept in registers whole kernel)
    const bf16* qrow = Qb + ((size_t)h * 2048 + q0 + w * 16 + lr) * 128;
    short8 qf[4];
    #pragma unroll
    for (int ks = 0; ks < 4; ++ks)
        qf[ks] = *(const short8*)(qrow + ks * 32 + lq * 8);

    floatx4 oacc[8] = {};
    float mrow[4] = {-1e30f, -1e30f, -1e30f, -1e30f};
    float lrow[4] = {0.f, 0.f, 0.f, 0.f};

    for (int kt = 0; kt < 32; ++kt) {
        const int kv0 = kt * 64;
        __syncthreads();
        // Ks: 64 rows x 16 chunks of 16B; source chunk pre-swizzled
        #pragma unroll
        for (int it = 0; it < 4; ++it) {
            const int c = tid + it * 256;
            const int row = c >> 4, cg = (c & 15) ^ (row & 7);
            load_lds16(Kb + ((size_t)h * 2048 + kv0 + row) * 128 + cg * 8,
                       Ks + c * 8);
        }
        // VsT: 128 rows x 8 chunks of 16B; source chunk pre-swizzled
        #pragma unroll
        for (int it = 0; it < 4; ++it) {
            const int c = tid + it * 256;
            const int row = c >> 3, cg = (c & 7) ^ (row & 7);
            load_lds16(Vb + ((size_t)h * 128 + row) * 2048 + kv0 + cg * 8,
                       VsT + c * 8);
        }
        __syncthreads();

        // S = Q K^T for 16 q x 64 kv
        floatx4 sacc[4] = {};
        __builtin_amdgcn_s_setprio(1);
        #pragma unroll
        for (int ks = 0; ks < 4; ++ks)
            #pragma unroll
            for (int jt = 0; jt < 4; ++jt) {
                const int row = jt * 16 + lr;
                short8 kf = *(const short8*)(
                    Ks + row * 128 + (((ks * 4 + lq) ^ (row & 7)) * 8));
                sacc[jt] = __builtin_amdgcn_mfma_f32_16x16x32_bf16(qf[ks], kf, sacc[jt], 0, 0, 0);
            }
        __builtin_amdgcn_s_setprio(0);

        // online softmax (lane holds rows lq*4+r, col lr of each 16-block)
        float alpha_r[4];
        #pragma unroll
        for (int r = 0; r < 4; ++r) {
            float s0 = sacc[0][r] * scale, s1 = sacc[1][r] * scale;
            float s2 = sacc[2][r] * scale, s3 = sacc[3][r] * scale;
            float mx = fmaxf(fmaxf(s0, s1), fmaxf(s2, s3));
            #pragma unroll
            for (int msk = 1; msk < 16; msk <<= 1)
                mx = fmaxf(mx, __shfl_xor(mx, msk));
            const float mn = fmaxf(mrow[r], mx);
            const float al = __expf(mrow[r] - mn);
            s0 = __expf(s0 - mn); s1 = __expf(s1 - mn);
            s2 = __expf(s2 - mn); s3 = __expf(s3 - mn);
            float sum = s0 + s1 + s2 + s3;
            #pragma unroll
            for (int msk = 1; msk < 16; msk <<= 1)
                sum += __shfl_xor(sum, msk);
            lrow[r] = lrow[r] * al + sum;
            mrow[r] = mn;
            alpha_r[r] = al;
            sacc[0][r] = s0; sacc[1][r] = s1; sacc[2][r] = s2; sacc[3][r] = s3;
        }
        #pragma unroll
        for (int nt = 0; nt < 8; ++nt)
            #pragma unroll
            for (int r = 0; r < 4; ++r) oacc[nt][r] *= alpha_r[r];

        // P: C-layout -> LDS (wave-private, swizzled) -> A-layout
        #pragma unroll
        for (int jt = 0; jt < 4; ++jt)
            #pragma unroll
            for (int r = 0; r < 4; ++r) {
                const int q = lq * 4 + r;
                const int ir = jt * 16 + lr;
                Ps[w][q * 64 + ((((ir >> 3) ^ (q & 7))) << 3) + (ir & 7)] =
                    __float2bfloat16(sacc[jt][r]);
            }
        // no barrier: Ps[w] is wave-private; same-wave DS ops are ordered

        short8 pf[2];
        #pragma unroll
        for (int k2 = 0; k2 < 2; ++k2)
            pf[k2] = *(const short8*)(
                &Ps[w][lr * 64 + (((k2 * 4 + lq) ^ (lr & 7)) << 3)]);
        __builtin_amdgcn_s_setprio(1);
        #pragma unroll
        for (int k2 = 0; k2 < 2; ++k2)
            #pragma unroll
            for (int nt = 0; nt < 8; ++nt) {
                const int row = nt * 16 + lr;
                short8 vf = *(const short8*)(
                    VsT + row * 64 + (((k2 * 4 + lq) ^ (row & 7)) * 8));
                oacc[nt] = __builtin_amdgcn_mfma_f32_16x16x32_bf16(pf[k2], vf, oacc[nt], 0, 0, 0);
            }
        __builtin_amdgcn_s_setprio(0);
    }

    // epilogue: O /= l (4 reciprocals), write bf16 [s][h*128+d]
    float rl[4];
    #pragma unroll
    for (int r = 0; r < 4; ++r) rl[r] = 1.0f / lrow[r];
    #pragma unroll
    for (int nt = 0; nt < 8; ++nt) {
        const int col = h * 128 + nt * 16 + lr;
        #pragma unroll
        for (int r = 0; r < 4; ++r) {
            const int s = q0 + w * 16 + lq * 4 + r;
            attnb[(size_t)s * 3072 + col] = __float2bfloat16(oacc[nt][r] * rl[r]);
        }
    }
}

// ---------------------------------------------------------------------------
extern "C" void kernel_launch(void* const* d_in, const int* in_sizes, int n_in,
                              void* d_out, int out_size, void* d_ws, size_t ws_size,
                              hipStream_t stream)
{
    (void)in_sizes; (void)n_in; (void)out_size; (void)ws_size;
    const float* hs        = (const float*)d_in[0];
    const float* ehs       = (const float*)d_in[1];
    const float* rc        = (const float*)d_in[2];
    const float* rs        = (const float*)d_in[3];
    const float* qkv_w     = (const float*)d_in[4];
    const float* qkv_down  = (const float*)d_in[5];
    const float* qkv_up    = (const float*)d_in[6];
    const float* aqkv_w    = (const float*)d_in[7];
    const float* aqkv_down = (const float*)d_in[8];
    const float* aqkv_up   = (const float*)d_in[9];
    const float* out_w     = (const float*)d_in[10];
    const float* out_down  = (const float*)d_in[11];
    const float* out_up    = (const float*)d_in[12];
    const float* out_b     = (const float*)d_in[13];
    const float* aout_w    = (const float*)d_in[14];
    const float* aout_down = (const float*)d_in[15];
    const float* aout_up   = (const float*)d_in[16];
    const float* aout_b    = (const float*)d_in[17];
    const float* nqw  = (const float*)d_in[18];
    const float* nkw  = (const float*)d_in[19];
    const float* naqw = (const float*)d_in[20];
    const float* nakw = (const float*)d_in[21];

    char* ws = (char*)d_ws;
    size_t o = 0;
    bf16* Qb = (bf16*)(ws + o); o += (size_t)24 * 2048 * 128 * 2;
    bf16* Kb = (bf16*)(ws + o); o += (size_t)24 * 2048 * 128 * 2;
    bf16* Vb = (bf16*)(ws + o); o += (size_t)24 * 2048 * 128 * 2;  // [h][d][s]
    bf16* attnb = (bf16*)(ws + o); o += (size_t)2048 * 3072 * 2;
    bf16* Xbi = (bf16*)(ws + o); o += (size_t)1536 * 3072 * 2;
    bf16* Xbt = (bf16*)(ws + o); o += (size_t)512 * 3072 * 2;
    bf16* Wq  = (bf16*)(ws + o); o += (size_t)9216 * 3072 * 2;
    bf16* Waq = (bf16*)(ws + o); o += (size_t)9216 * 3072 * 2;
    // out-proj weights alias the QKV weight region (converted AFTER QKV GEMMs;
    // stream order guarantees the QKV GEMMs have finished reading Wq/Waq).
    bf16* Wo  = Wq;
    bf16* Wao = Wq + (size_t)3072 * 3072;
    bf16* t_img  = (bf16*)(ws + o); o += (size_t)1536 * 32 * 2;
    bf16* t_txt  = (bf16*)(ws + o); o += (size_t)512 * 32 * 2;
    bf16* t2_img = (bf16*)(ws + o); o += (size_t)1536 * 32 * 2;
    bf16* t2_txt = (bf16*)(ws + o); o += (size_t)512 * 32 * 2;
    bf16* upTq  = (bf16*)(ws + o); o += (size_t)9216 * 32 * 2;
    bf16* upTaq = (bf16*)(ws + o); o += (size_t)9216 * 32 * 2;
    bf16* upTo  = (bf16*)(ws + o); o += (size_t)3072 * 32 * 2;
    bf16* upTao = (bf16*)(ws + o); o += (size_t)3072 * 32 * 2;

    // one-time f32 -> bf16 conversions (activations + QKV weights)
    cvt_bf16<<<2304, 256, 0, stream>>>(hs, Xbi);          // 1536*3072
    cvt_bf16<<<768, 256, 0, stream>>>(ehs, Xbt);          // 512*3072
    cvt_bf16<<<13824, 256, 0, stream>>>(qkv_w, Wq);       // 9216*3072
    cvt_bf16<<<13824, 256, 0, stream>>>(aqkv_w, Waq);

    transposeR<<<144, 64, 0, stream>>>(qkv_up, upTq, 9216);
    transposeR<<<144, 64, 0, stream>>>(aqkv_up, upTaq, 9216);
    transposeR<<<48, 64, 0, stream>>>(out_up, upTo, 3072);
    transposeR<<<48, 64, 0, stream>>>(aout_up, upTao, 3072);
    downproj<<<1536, 256, 0, stream>>>(Xbi, qkv_down, t_img, 3072);
    downproj<<<512, 256, 0, stream>>>(Xbt, aqkv_down, t_txt, 3072);

    // merged QKV GEMM: by 0..11 img (s_base 512), by 12..15 txt (s_base 0)
    gemm128<<<dim3(72, 16), 256, 0, stream>>>(
        Xbi, Wq, t_img, upTq,
        Xbt, Waq, t_txt, upTaq,
        nullptr, nullptr, nullptr, nullptr,
        Qb, Kb, Vb, 12, 9216, 3072, 512, 0, 1);

    // now safe to overwrite Wq/Waq region with out-proj weights
    cvt_bf16<<<4608, 256, 0, stream>>>(out_w, Wo);        // 3072*3072
    cvt_bf16<<<4608, 256, 0, stream>>>(aout_w, Wao);

    rmsrope<<<12288, 256, 0, stream>>>(Qb, Kb, rc, rs, nqw, nkw, naqw, nakw);

    attn64<<<dim3(32, 24), 256, 0, stream>>>(Qb, Kb, Vb, attnb);

    downproj<<<1536, 256, 0, stream>>>(attnb + (size_t)512 * 3072, out_down, t2_img, 3072);
    downproj<<<512, 256, 0, stream>>>(attnb, aout_down, t2_txt, 3072);

    // merged out-proj GEMM: by 0..11 img -> C0, by 12..15 txt -> C1
    float* outp = (float*)d_out;
    gemm128<<<dim3(24, 16), 256, 0, stream>>>(
        attnb + (size_t)512 * 3072, Wo, t2_img, upTo,
        attnb,                      Wao, t2_txt, upTao,
        out_b, aout_b, outp, outp + (size_t)1536 * 3072,
        nullptr, nullptr, nullptr, 12, 3072, 3072, 0, 0, 0);
}

// Round 6
// 951.059 us; speedup vs baseline: 1.2298x; 1.0030x over previous
//
#include <hip/hip_runtime.h>
#include <hip/hip_bf16.h>
#include <stdint.h>

// Problem: B=1, S_IMG=1536, S_TXT=512, D=3072, H=24, HD=128, R=32.
// Harness dtypes: ALL inputs float32, output float32. Internal MFMA in bf16.
typedef __hip_bfloat16 bf16;
typedef __attribute__((ext_vector_type(8))) short short8;   // 8 bf16 (16B)
typedef __attribute__((ext_vector_type(4))) short short4b;  // 4 bf16 (8B)
typedef __attribute__((ext_vector_type(4))) float floatx4;  // MFMA C/D

__device__ __forceinline__ short bfs(float x) {
    // RNE f32 -> bf16, returned as raw bits
    uint32_t u = __builtin_bit_cast(uint32_t, x);
    u += 0x7FFFu + ((u >> 16) & 1u);
    return (short)(u >> 16);
}
__device__ __forceinline__ float b2f(bf16 x) { return __bfloat162float(x); }

// async global->LDS, 16B per lane. LDS dest is wave-uniform base + lane*16,
// so per-lane dest pointers must be exactly base + lane*16 (linear layout).
__device__ __forceinline__ void load_lds16(const bf16* g, bf16* l) {
    __builtin_amdgcn_global_load_lds(
        (const __attribute__((address_space(1))) uint32_t*)g,
        (__attribute__((address_space(3))) uint32_t*)l, 16, 0, 0);
}

#define PHASE_BARRIER() do { __builtin_amdgcn_s_barrier(); \
                             __builtin_amdgcn_sched_barrier(0); } while (0)

// ---------------------------------------------------------------------------
// f32 -> bf16 bulk convert. 8 elems/thread, grid = n/2048 blocks.
__global__ __launch_bounds__(256) void cvt_bf16(const float* __restrict__ X,
                                                bf16* __restrict__ Y) {
    const size_t i = ((size_t)blockIdx.x * 256 + threadIdx.x) * 8;
    const float4 v0 = *(const float4*)(X + i);
    const float4 v1 = *(const float4*)(X + i + 4);
    short8 o = { bfs(v0.x), bfs(v0.y), bfs(v0.z), bfs(v0.w),
                 bfs(v1.x), bfs(v1.y), bfs(v1.z), bfs(v1.w) };
    *(short8*)(Y + i) = o;
}

// ---------------------------------------------------------------------------
// upT[n][r] = up[r][n], padded to 64 cols (cols 32..63 zero) so the low-rank
// term is a normal BK=64 K-tile in the GEMM.
__global__ __launch_bounds__(64) void transposeR(const float* __restrict__ U,
                                                 bf16* __restrict__ UT, int N) {
    const int n = blockIdx.x * 64 + threadIdx.x;
    #pragma unroll
    for (int r = 0; r < 32; ++r) {
        UT[(size_t)n * 64 + r] = __float2bfloat16(U[(size_t)r * N + n]);
        UT[(size_t)n * 64 + 32 + r] = __float2bfloat16(0.0f);
    }
}

// ---------------------------------------------------------------------------
// t[m][r] = sum_k x[m][k] * down[k][r]   (K=3072, R=32). One block per row m.
// x is bf16, down is f32, t written bf16 padded to 64 cols (upper 32 zero).
__global__ __launch_bounds__(256) void downproj(const bf16* __restrict__ X,
                                                const float* __restrict__ Dn,
                                                bf16* __restrict__ T, int K) {
    const int m = blockIdx.x;
    const int n = threadIdx.x & 31;
    const int kg = threadIdx.x >> 5;           // 8 K-groups
    const bf16* x = X + (size_t)m * K;
    const int kc = K >> 3;                     // 384
    float acc = 0.f;
    #pragma unroll 4
    for (int k = kg * kc; k < (kg + 1) * kc; ++k)
        acc += b2f(x[k]) * Dn[(size_t)k * 32 + n];
    __shared__ float red[8][32];
    red[kg][n] = acc;
    __syncthreads();
    if (threadIdx.x < 32) {
        float s = 0.f;
        #pragma unroll
        for (int g = 0; g < 8; ++g) s += red[g][n];
        T[(size_t)m * 64 + n] = __float2bfloat16(s);
        T[(size_t)m * 64 + 32 + n] = __float2bfloat16(0.0f);
    }
}

// ---------------------------------------------------------------------------
// Two fused GEMMs in one dispatch (set 0 = img, set 1 = txt), selected by
// m-tile index. C = A @ B^T + t @ upT^T (+bias). A:[M][K], B:[N][K] bf16;
// t:[M][64] and upT:[N][64] zero-padded so low-rank = K-tile index ksteps.
// Structure: 128x128 tile, BK=64, double-buffered K-tiles, 4 phases/K-tile:
//   phase p: {ds_read frags (row-XOR swizzled, conflict-free) ; issue 2
//   global_load_lds of next tile ; s_barrier ; setprio(1) 8xMFMA setprio(0)}
// One __syncthreads (vmcnt0 drain) per K-tile. LDS 64KB -> 2 blocks/CU.
// mode 0: write C row-major f32. mode 1: scatter Q/K [h][s][128], V^T.
__global__ __launch_bounds__(256) void gemm64k(
    const bf16* __restrict__ A0, const bf16* __restrict__ B0,
    const bf16* __restrict__ T0, const bf16* __restrict__ U0,
    const bf16* __restrict__ A1, const bf16* __restrict__ B1,
    const bf16* __restrict__ T1, const bf16* __restrict__ U1,
    const float* __restrict__ bias0, const float* __restrict__ bias1,
    float* __restrict__ C0, float* __restrict__ C1,
    bf16* __restrict__ Qb, bf16* __restrict__ Kb, bf16* __restrict__ Vb,
    int mtiles0, int N, int K, int sb0, int sb1, int mode)
{
    __shared__ __align__(16) bf16 As[2][128 * 64];   // 32 KB
    __shared__ __align__(16) bf16 Bs[2][128 * 64];   // 32 KB
    const int tid = threadIdx.x;
    const int lane = tid & 63, w = tid >> 6;
    const int wm = (w >> 1) * 64, wn = (w & 1) * 64;
    const int lr = lane & 15, lq = lane >> 4;

    // XCD-aware bijective swizzle (all grids here have nwg % 8 == 0)
    int bid = blockIdx.y * gridDim.x + blockIdx.x;
    const int cpx = (gridDim.x * gridDim.y) >> 3;
    bid = (bid & 7) * cpx + (bid >> 3);
    const int by = bid / gridDim.x, bx = bid - by * gridDim.x;

    const bool set1 = (by >= mtiles0);
    const int lby = set1 ? (by - mtiles0) : by;
    const int m0 = lby * 128, n0 = bx * 128;
    const bf16* Asel = set1 ? A1 : A0;
    const bf16* Bsel = set1 ? B1 : B0;
    const bf16* Tsel = set1 ? T1 : T0;
    const bf16* Usel = set1 ? U1 : U0;
    const int s_base = set1 ? sb1 : sb0;

    const int ksteps = K >> 6;                 // full BK=64 tiles; +1 low-rank

    // stage half of A-tile (part 0: chunks 0..511, part 1: 512..1023)
    // chunk c -> LDS linear c*8 ; source col-chunk cg = (c&7)^(row&7)
    auto stageA = [&](int buf, int kt, int part) {
        const bf16* src; int ld;
        if (kt < ksteps) { src = Asel + (size_t)m0 * K + kt * 64; ld = K; }
        else             { src = Tsel + (size_t)m0 * 64;          ld = 64; }
        bf16* dst = &As[buf][0];
        #pragma unroll
        for (int it = 0; it < 2; ++it) {
            const int c = tid + part * 512 + it * 256;
            const int row = c >> 3, cg = (c & 7) ^ (row & 7);
            load_lds16(src + (size_t)row * ld + cg * 8, dst + c * 8);
        }
    };
    auto stageB = [&](int buf, int kt, int part) {
        const bf16* src; int ld;
        if (kt < ksteps) { src = Bsel + (size_t)n0 * K + kt * 64; ld = K; }
        else             { src = Usel + (size_t)n0 * 64;          ld = 64; }
        bf16* dst = &Bs[buf][0];
        #pragma unroll
        for (int it = 0; it < 2; ++it) {
            const int c = tid + part * 512 + it * 256;
            const int row = c >> 3, cg = (c & 7) ^ (row & 7);
            load_lds16(src + (size_t)row * ld + cg * 8, dst + c * 8);
        }
    };

    floatx4 acc[4][4] = {};
    short8 bfr[4][2];

    // prologue: stage K-tile 0 fully into buf 0
    stageA(0, 0, 0); stageA(0, 0, 1);
    stageB(0, 0, 0); stageB(0, 0, 1);
    __syncthreads();

    for (int kt = 0; kt <= ksteps; ++kt) {
        const int buf = kt & 1, nbuf = buf ^ 1;
        const bool more = (kt < ksteps);
        const bf16* Ac = &As[buf][0];
        const bf16* Bc = &Bs[buf][0];

        auto readA = [&](int p, short8 af[2]) {
            const int row = wm + p * 16 + lr;
            #pragma unroll
            for (int k2 = 0; k2 < 2; ++k2)
                af[k2] = *(const short8*)(
                    Ac + row * 64 + (((k2 * 4 + lq) ^ (row & 7)) << 3));
        };
        auto mfmaP = [&](int p, short8 af[2]) {
            __builtin_amdgcn_s_setprio(1);
            #pragma unroll
            for (int k2 = 0; k2 < 2; ++k2)
                #pragma unroll
                for (int j = 0; j < 4; ++j)
                    acc[p][j] = __builtin_amdgcn_mfma_f32_16x16x32_bf16(
                        af[k2], bfr[j][k2], acc[p][j], 0, 0, 0);
            __builtin_amdgcn_s_setprio(0);
        };

        short8 af[2];
        // ---- phase 0: B frags (8 reads) + A m-frag 0; stage A part 0
        #pragma unroll
        for (int j = 0; j < 4; ++j) {
            const int row = wn + j * 16 + lr;
            #pragma unroll
            for (int k2 = 0; k2 < 2; ++k2)
                bfr[j][k2] = *(const short8*)(
                    Bc + row * 64 + (((k2 * 4 + lq) ^ (row & 7)) << 3));
        }
        readA(0, af);
        if (more) stageA(nbuf, kt + 1, 0);
        PHASE_BARRIER();
        mfmaP(0, af);
        // ---- phase 1
        readA(1, af);
        if (more) stageA(nbuf, kt + 1, 1);
        PHASE_BARRIER();
        mfmaP(1, af);
        // ---- phase 2
        readA(2, af);
        if (more) stageB(nbuf, kt + 1, 0);
        PHASE_BARRIER();
        mfmaP(2, af);
        // ---- phase 3
        readA(3, af);
        if (more) stageB(nbuf, kt + 1, 1);
        PHASE_BARRIER();
        mfmaP(3, af);
        __syncthreads();     // vmcnt(0)+lgkmcnt(0)+barrier: next tile resident
    }

    if (mode == 0) {
        float* Csel = set1 ? C1 : C0;
        const float* bsel = set1 ? bias1 : bias0;
        #pragma unroll
        for (int j = 0; j < 4; ++j) {
            const int col = n0 + wn + j * 16 + lr;
            const float bv = bsel ? bsel[col] : 0.0f;
            #pragma unroll
            for (int i = 0; i < 4; ++i) {
                const int rowb = m0 + wm + i * 16 + lq * 4;
                #pragma unroll
                for (int r = 0; r < 4; ++r)
                    Csel[(size_t)(rowb + r) * N + col] = acc[i][j][r] + bv;
            }
        }
    } else {
        #pragma unroll
        for (int j = 0; j < 4; ++j) {
            const int col = n0 + wn + j * 16 + lr;
            const int which = col / 3072;           // uniform per block (128 | 3072)
            const int cc = col - which * 3072;
            const int hh = cc >> 7, dd = cc & 127;
            #pragma unroll
            for (int i = 0; i < 4; ++i) {
                const int rowb = m0 + wm + i * 16 + lq * 4;
                const int s0 = s_base + rowb;
                if (which == 2) {
                    // V^T: 4 consecutive s per lane -> one 8B store
                    short4b pv = { bfs(acc[i][j][0]), bfs(acc[i][j][1]),
                                   bfs(acc[i][j][2]), bfs(acc[i][j][3]) };
                    *(short4b*)(Vb + ((size_t)hh * 128 + dd) * 2048 + s0) = pv;
                } else {
                    bf16* dst = (which == 0 ? Qb : Kb)
                              + ((size_t)hh * 2048 + s0) * 128 + dd;
                    #pragma unroll
                    for (int r = 0; r < 4; ++r)
                        dst[(size_t)r * 128] = __float2bfloat16(acc[i][j][r]);
                }
            }
        }
    }
}

// ---------------------------------------------------------------------------
// RMSNorm (per (s,h) row of 128) + RoPE, in-place on Q and K (bf16 buffers).
// 4 rows per block (one per wave), 256 threads.
__global__ __launch_bounds__(256) void rmsrope(
    bf16* __restrict__ Qb, bf16* __restrict__ Kb,
    const float* __restrict__ cosb, const float* __restrict__ sinb,
    const float* __restrict__ nqw, const float* __restrict__ nkw,
    const float* __restrict__ naqw, const float* __restrict__ nakw)
{
    const int idx = blockIdx.x * 4 + (threadIdx.x >> 6);
    const int i = threadIdx.x & 63;                  // pair index 0..63
    const int s = idx & 2047;
    const int h = idx >> 11;
    const float c  = cosb[s * 64 + i];
    const float sn = sinb[s * 64 + i];
    const bool txt = (s < 512);
    const size_t base = ((size_t)h * 2048 + s) * 128;

    {
        __hip_bfloat162* row = (__hip_bfloat162*)(Qb + base);
        __hip_bfloat162 pv = row[i];
        float x0 = b2f(pv.x), x1 = b2f(pv.y);
        float ss = x0 * x0 + x1 * x1;
        #pragma unroll
        for (int m = 1; m < 64; m <<= 1) ss += __shfl_xor(ss, m);
        const float rms = rsqrtf(ss * (1.0f / 128.0f) + 1e-5f);
        const float2 nw = *(const float2*)((txt ? naqw : nqw) + 2 * i);
        const float y0 = x0 * rms * nw.x;
        const float y1 = x1 * rms * nw.y;
        __hip_bfloat162 o;
        o.x = __float2bfloat16(y0 * c - y1 * sn);
        o.y = __float2bfloat16(y0 * sn + y1 * c);
        row[i] = o;
    }
    {
        __hip_bfloat162* row = (__hip_bfloat162*)(Kb + base);
        __hip_bfloat162 pv = row[i];
        float x0 = b2f(pv.x), x1 = b2f(pv.y);
        float ss = x0 * x0 + x1 * x1;
        #pragma unroll
        for (int m = 1; m < 64; m <<= 1) ss += __shfl_xor(ss, m);
        const float rms = rsqrtf(ss * (1.0f / 128.0f) + 1e-5f);
        const float2 nw = *(const float2*)((txt ? nakw : nkw) + 2 * i);
        const float y0 = x0 * rms * nw.x;
        const float y1 = x1 * rms * nw.y;
        __hip_bfloat162 o;
        o.x = __float2bfloat16(y0 * c - y1 * sn);
        o.y = __float2bfloat16(y0 * sn + y1 * c);
        row[i] = o;
    }
}

// ---------------------------------------------------------------------------
// Flash attention: block = 64 q-rows of one head; KV tiles of 64; 4 waves,
// each wave owns 16 q-rows x full HD=128. Online softmax in registers.
// Output attnb is bf16 [s][3072]. K/V staged via global_load_lds with the
// 16B-chunk XOR swizzle (chunk ^= row&7) applied to the GLOBAL source (LDS
// dest must stay linear) and to every ds_read address (rule #21 / T2).
__global__ __launch_bounds__(256) void attn64(
    const bf16* __restrict__ Qb, const bf16* __restrict__ Kb,
    const bf16* __restrict__ Vb, bf16* __restrict__ attnb)
{
    __shared__ __align__(16) bf16 Ks[64 * 128];     // [kv][d], swizzled
    __shared__ __align__(16) bf16 VsT[128 * 64];    // [d][kv], swizzled
    __shared__ __align__(16) bf16 Ps[4][16 * 64];   // per-wave P, swizzled
    const int tid = threadIdx.x, lane = tid & 63, w = tid >> 6;
    const int lr = lane & 15, lq = lane >> 4;
    const int h = blockIdx.y, q0 = blockIdx.x * 64;
    const float scale = 0.08838834764831845f;   // 1/sqrt(128)

    // Q fragments for this wave's 16 rows (kept in registers whole kernel)
    const bf16* qrow = Qb + ((size_t)h * 2048 + q0 + w * 16 + lr) * 128;
    short8 qf[4];
    #pragma unroll
    for (int ks = 0; ks < 4; ++ks)
        qf[ks] = *(const short8*)(qrow + ks * 32 + lq * 8);

    floatx4 oacc[8] = {};
    float mrow[4] = {-1e30f, -1e30f, -1e30f, -1e30f};
    float lrow[4] = {0.f, 0.f, 0.f, 0.f};

    for (int kt = 0; kt < 32; ++kt) {
        const int kv0 = kt * 64;
        __syncthreads();
        // Ks: 64 rows x 16 chunks of 16B; source chunk pre-swizzled
        #pragma unroll
        for (int it = 0; it < 4; ++it) {
            const int c = tid + it * 256;
            const int row = c >> 4, cg = (c & 15) ^ (row & 7);
            load_lds16(Kb + ((size_t)h * 2048 + kv0 + row) * 128 + cg * 8,
                       Ks + c * 8);
        }
        // VsT: 128 rows x 8 chunks of 16B; source chunk pre-swizzled
        #pragma unroll
        for (int it = 0; it < 4; ++it) {
            const int c = tid + it * 256;
            const int row = c >> 3, cg = (c & 7) ^ (row & 7);
            load_lds16(Vb + ((size_t)h * 128 + row) * 2048 + kv0 + cg * 8,
                       VsT + c * 8);
        }
        __syncthreads();

        // S = Q K^T for 16 q x 64 kv
        floatx4 sacc[4] = {};
        __builtin_amdgcn_s_setprio(1);
        #pragma unroll
        for (int ks = 0; ks < 4; ++ks)
            #pragma unroll
            for (int jt = 0; jt < 4; ++jt) {
                const int row = jt * 16 + lr;
                short8 kf = *(const short8*)(
                    Ks + row * 128 + (((ks * 4 + lq) ^ (row & 7)) * 8));
                sacc[jt] = __builtin_amdgcn_mfma_f32_16x16x32_bf16(qf[ks], kf, sacc[jt], 0, 0, 0);
            }
        __builtin_amdgcn_s_setprio(0);

        // online softmax (lane holds rows lq*4+r, col lr of each 16-block)
        float alpha_r[4];
        #pragma unroll
        for (int r = 0; r < 4; ++r) {
            float s0 = sacc[0][r] * scale, s1 = sacc[1][r] * scale;
            float s2 = sacc[2][r] * scale, s3 = sacc[3][r] * scale;
            float mx = fmaxf(fmaxf(s0, s1), fmaxf(s2, s3));
            #pragma unroll
            for (int msk = 1; msk < 16; msk <<= 1)
                mx = fmaxf(mx, __shfl_xor(mx, msk));
            const float mn = fmaxf(mrow[r], mx);
            const float al = __expf(mrow[r] - mn);
            s0 = __expf(s0 - mn); s1 = __expf(s1 - mn);
            s2 = __expf(s2 - mn); s3 = __expf(s3 - mn);
            float sum = s0 + s1 + s2 + s3;
            #pragma unroll
            for (int msk = 1; msk < 16; msk <<= 1)
                sum += __shfl_xor(sum, msk);
            lrow[r] = lrow[r] * al + sum;
            mrow[r] = mn;
            alpha_r[r] = al;
            sacc[0][r] = s0; sacc[1][r] = s1; sacc[2][r] = s2; sacc[3][r] = s3;
        }
        #pragma unroll
        for (int nt = 0; nt < 8; ++nt)
            #pragma unroll
            for (int r = 0; r < 4; ++r) oacc[nt][r] *= alpha_r[r];

        // P: C-layout -> LDS (wave-private, swizzled) -> A-layout
        #pragma unroll
        for (int jt = 0; jt < 4; ++jt)
            #pragma unroll
            for (int r = 0; r < 4; ++r) {
                const int q = lq * 4 + r;
                const int ir = jt * 16 + lr;
                Ps[w][q * 64 + ((((ir >> 3) ^ (q & 7))) << 3) + (ir & 7)] =
                    __float2bfloat16(sacc[jt][r]);
            }
        // no barrier: Ps[w] is wave-private; same-wave DS ops are ordered

        short8 pf[2];
        #pragma unroll
        for (int k2 = 0; k2 < 2; ++k2)
            pf[k2] = *(const short8*)(
                &Ps[w][lr * 64 + (((k2 * 4 + lq) ^ (lr & 7)) << 3)]);
        __builtin_amdgcn_s_setprio(1);
        #pragma unroll
        for (int k2 = 0; k2 < 2; ++k2)
            #pragma unroll
            for (int nt = 0; nt < 8; ++nt) {
                const int row = nt * 16 + lr;
                short8 vf = *(const short8*)(
                    VsT + row * 64 + (((k2 * 4 + lq) ^ (row & 7)) * 8));
                oacc[nt] = __builtin_amdgcn_mfma_f32_16x16x32_bf16(pf[k2], vf, oacc[nt], 0, 0, 0);
            }
        __builtin_amdgcn_s_setprio(0);
    }

    // epilogue: O /= l (4 reciprocals), write bf16 [s][h*128+d]
    float rl[4];
    #pragma unroll
    for (int r = 0; r < 4; ++r) rl[r] = 1.0f / lrow[r];
    #pragma unroll
    for (int nt = 0; nt < 8; ++nt) {
        const int col = h * 128 + nt * 16 + lr;
        #pragma unroll
        for (int r = 0; r < 4; ++r) {
            const int s = q0 + w * 16 + lq * 4 + r;
            attnb[(size_t)s * 3072 + col] = __float2bfloat16(oacc[nt][r] * rl[r]);
        }
    }
}

// ---------------------------------------------------------------------------
extern "C" void kernel_launch(void* const* d_in, const int* in_sizes, int n_in,
                              void* d_out, int out_size, void* d_ws, size_t ws_size,
                              hipStream_t stream)
{
    (void)in_sizes; (void)n_in; (void)out_size; (void)ws_size;
    const float* hs        = (const float*)d_in[0];
    const float* ehs       = (const float*)d_in[1];
    const float* rc        = (const float*)d_in[2];
    const float* rs        = (const float*)d_in[3];
    const float* qkv_w     = (const float*)d_in[4];
    const float* qkv_down  = (const float*)d_in[5];
    const float* qkv_up    = (const float*)d_in[6];
    const float* aqkv_w    = (const float*)d_in[7];
    const float* aqkv_down = (const float*)d_in[8];
    const float* aqkv_up   = (const float*)d_in[9];
    const float* out_w     = (const float*)d_in[10];
    const float* out_down  = (const float*)d_in[11];
    const float* out_up    = (const float*)d_in[12];
    const float* out_b     = (const float*)d_in[13];
    const float* aout_w    = (const float*)d_in[14];
    const float* aout_down = (const float*)d_in[15];
    const float* aout_up   = (const float*)d_in[16];
    const float* aout_b    = (const float*)d_in[17];
    const float* nqw  = (const float*)d_in[18];
    const float* nkw  = (const float*)d_in[19];
    const float* naqw = (const float*)d_in[20];
    const float* nakw = (const float*)d_in[21];

    char* ws = (char*)d_ws;
    size_t o = 0;
    bf16* Qb = (bf16*)(ws + o); o += (size_t)24 * 2048 * 128 * 2;
    bf16* Kb = (bf16*)(ws + o); o += (size_t)24 * 2048 * 128 * 2;
    bf16* Vb = (bf16*)(ws + o); o += (size_t)24 * 2048 * 128 * 2;  // [h][d][s]
    bf16* attnb = (bf16*)(ws + o); o += (size_t)2048 * 3072 * 2;
    bf16* Xbi = (bf16*)(ws + o); o += (size_t)1536 * 3072 * 2;
    bf16* Xbt = (bf16*)(ws + o); o += (size_t)512 * 3072 * 2;
    bf16* Wq  = (bf16*)(ws + o); o += (size_t)9216 * 3072 * 2;
    bf16* Waq = (bf16*)(ws + o); o += (size_t)9216 * 3072 * 2;
    // out-proj weights alias the QKV weight region (converted AFTER QKV GEMMs;
    // stream order guarantees the QKV GEMMs have finished reading Wq/Waq).
    bf16* Wo  = Wq;
    bf16* Wao = Wq + (size_t)3072 * 3072;
    bf16* t_img  = (bf16*)(ws + o); o += (size_t)1536 * 64 * 2;
    bf16* t_txt  = (bf16*)(ws + o); o += (size_t)512 * 64 * 2;
    bf16* t2_img = (bf16*)(ws + o); o += (size_t)1536 * 64 * 2;
    bf16* t2_txt = (bf16*)(ws + o); o += (size_t)512 * 64 * 2;
    bf16* upTq  = (bf16*)(ws + o); o += (size_t)9216 * 64 * 2;
    bf16* upTaq = (bf16*)(ws + o); o += (size_t)9216 * 64 * 2;
    bf16* upTo  = (bf16*)(ws + o); o += (size_t)3072 * 64 * 2;
    bf16* upTao = (bf16*)(ws + o); o += (size_t)3072 * 64 * 2;

    // one-time f32 -> bf16 conversions (activations + QKV weights)
    cvt_bf16<<<2304, 256, 0, stream>>>(hs, Xbi);          // 1536*3072
    cvt_bf16<<<768, 256, 0, stream>>>(ehs, Xbt);          // 512*3072
    cvt_bf16<<<13824, 256, 0, stream>>>(qkv_w, Wq);       // 9216*3072
    cvt_bf16<<<13824, 256, 0, stream>>>(aqkv_w, Waq);

    transposeR<<<144, 64, 0, stream>>>(qkv_up, upTq, 9216);
    transposeR<<<144, 64, 0, stream>>>(aqkv_up, upTaq, 9216);
    transposeR<<<48, 64, 0, stream>>>(out_up, upTo, 3072);
    transposeR<<<48, 64, 0, stream>>>(aout_up, upTao, 3072);
    downproj<<<1536, 256, 0, stream>>>(Xbi, qkv_down, t_img, 3072);
    downproj<<<512, 256, 0, stream>>>(Xbt, aqkv_down, t_txt, 3072);

    // merged QKV GEMM: by 0..11 img (s_base 512), by 12..15 txt (s_base 0)
    gemm64k<<<dim3(72, 16), 256, 0, stream>>>(
        Xbi, Wq, t_img, upTq,
        Xbt, Waq, t_txt, upTaq,
        nullptr, nullptr, nullptr, nullptr,
        Qb, Kb, Vb, 12, 9216, 3072, 512, 0, 1);

    // now safe to overwrite Wq/Waq region with out-proj weights
    cvt_bf16<<<4608, 256, 0, stream>>>(out_w, Wo);        // 3072*3072
    cvt_bf16<<<4608, 256, 0, stream>>>(aout_w, Wao);

    rmsrope<<<12288, 256, 0, stream>>>(Qb, Kb, rc, rs, nqw, nkw, naqw, nakw);

    attn64<<<dim3(32, 24), 256, 0, stream>>>(Qb, Kb, Vb, attnb);

    downproj<<<1536, 256, 0, stream>>>(attnb + (size_t)512 * 3072, out_down, t2_img, 3072);
    downproj<<<512, 256, 0, stream>>>(attnb, aout_down, t2_txt, 3072);

    // merged out-proj GEMM: by 0..11 img -> C0, by 12..15 txt -> C1
    float* outp = (float*)d_out;
    gemm64k<<<dim3(24, 16), 256, 0, stream>>>(
        attnb + (size_t)512 * 3072, Wo, t2_img, upTo,
        attnb,                      Wao, t2_txt, upTao,
        out_b, aout_b, outp, outp + (size_t)1536 * 3072,
        nullptr, nullptr, nullptr, 12, 3072, 3072, 0, 0, 0);
}